// Round 10
// baseline (1143.474 us; speedup 1.0000x reference)
//
#include <hip/hip_runtime.h>
#include <hip/hip_bf16.h>
#include <stdint.h>

// ---------------------------------------------------------------------------
// MMTransformer: B=32, IMG_LEN=49, TXT_LEN=77, L=126, D=512, H=8, HK=64,
// FF=2048, NB=4, IMG_DIM=768, VOCAB=49408.
// Round 10: launch-count 42 -> 26. (1) LN fused into consuming GEMMs
// (gemm_lna_kernel: per-block row-stats prologue + LN transform in reg-staged
// A-path, T14 issue-early/write-late, counted vmcnt); (2) prep_all merges
// weight transposes + img convert + txt embed. Retained: counted-vmcnt
// pipelines, 256^2 vocab GEMM, chunk-XOR LDS swizzle, bijective XCD swizzle,
// LDS-coalesced epilogues, runtime dtype detection.
// ---------------------------------------------------------------------------

using u16 = unsigned short;
typedef __attribute__((ext_vector_type(8))) __bf16 bf16x8v;
typedef __attribute__((ext_vector_type(4))) float f32x4;

__device__ __forceinline__ float bf2f(u16 u) {
  union { unsigned int i; float f; } x; x.i = ((unsigned int)u) << 16; return x.f;
}
__device__ __forceinline__ u16 f2bf(float f) {
  union { float f; unsigned int i; } u; u.f = f;
  unsigned int r = u.i + 0x7FFFu + ((u.i >> 16) & 1u);   // RNE
  return (u16)(r >> 16);
}
__device__ __forceinline__ float ld_f(const void* p, size_t i, int fl) {
  return fl ? ((const float*)p)[i] : bf2f(((const u16*)p)[i]);
}
__device__ __forceinline__ u16 ld_bf(const void* p, size_t i, int fl) {
  return fl ? f2bf(((const float*)p)[i]) : ((const u16*)p)[i];
}

__device__ __forceinline__ void async_copy16(const void* g, void* l) {
  __builtin_amdgcn_global_load_lds(
      (__attribute__((address_space(1))) void*)(g),
      (__attribute__((address_space(3))) void*)(l), 16, 0, 0);
}

__global__ void detect_kernel(const void* __restrict__ img, int* __restrict__ flag) {
  const int lane = threadIdx.x;
  const u16* p = (const u16*)img;
  int bad = 0;
#pragma unroll
  for (int i = 0; i < 4; ++i) {
    float v = bf2f(p[lane * 4 + i]);
    float av = fabsf(v);
    if (!(av <= 1e4f) || (av != 0.0f && av < 1e-30f)) bad++;
  }
#pragma unroll
  for (int off = 32; off; off >>= 1) bad += __shfl_xor(bad, off, 64);
  if (lane == 0) flag[0] = (bad > 16) ? 1 : 0;
}

__global__ void sentinel_kernel(float* out) {
  out[blockIdx.x * 256 + threadIdx.x] = 123456.0f;
}

// ---------------------------------------------------------------------------
// Layer GEMM (bf16 A): BN=128, BK=64, counted-vmcnt 2-buffer pipeline.
// EPI 2: acc+bias+resid -> f32. EPI 3: img embed f32 (+pos, row remap).
// ---------------------------------------------------------------------------
template <int BM, int BN, int EPI>
__global__ __launch_bounds__(256) void gemm_kernel(
    const u16* __restrict__ A, const u16* __restrict__ Bt, void* Cout,
    const void* __restrict__ bias, long boff, const float* resid,
    const void* __restrict__ pos, int M, int N, int K, int gridM,
    const int* __restrict__ fl)
{
  static_assert(BN == 128, "");
  static_assert(BM == 64 || BM == 128, "");
  constexpr int TILE_B = (BM + BN) * 128;
  constexpr int EPI_B = BM * BN * 2;
  constexpr int SMEM_B = (2 * TILE_B > EPI_B) ? 2 * TILE_B : EPI_B;
  __shared__ __align__(16) char smem[SMEM_B];

  const int tid = threadIdx.x;
  const int lane = tid & 63, wid = tid >> 6;
  const int wm = wid >> 1, wn = wid & 1;
  constexpr int FM = BM / 32, FN = 4;
  constexpr int ITA = BM / 32, ITB = BN / 32;
  constexpr int NLOADS = ITA + ITB;

  const int nwg = gridDim.x;
  const int q = nwg >> 3, r8 = nwg & 7;
  const int xcd = blockIdx.x & 7, idx = blockIdx.x >> 3;
  const int wgid = (xcd < r8 ? xcd * (q + 1) : r8 * (q + 1) + (xcd - r8) * q) + idx;
  const int tileM = (wgid % gridM) * BM, tileN = (wgid / gridM) * BN;

  f32x4 acc[FM][FN] = {};

  auto stage = [&](int buf, int kt) {
    char* base = smem + buf * TILE_B;
#pragma unroll
    for (int it = 0; it < ITA; ++it) {
      int ch = (wid * ITA + it) * 64 + lane;
      int row = ch >> 3, slot = ch & 7;
      int grow = tileM + row; grow = grow < M ? grow : (M - 1);
      async_copy16(A + (size_t)grow * K + kt * 64 + ((slot ^ (row & 7)) << 3),
                   base + (wid * ITA + it) * 1024);
    }
#pragma unroll
    for (int it = 0; it < ITB; ++it) {
      int ch = (wid * ITB + it) * 64 + lane;
      int row = ch >> 3, slot = ch & 7;
      async_copy16(Bt + (size_t)(tileN + row) * K + kt * 64 + ((slot ^ (row & 7)) << 3),
                   base + BM * 128 + (wid * ITB + it) * 1024);
    }
  };

  const int kSteps = K >> 6;
  stage(0, 0);
  int cur = 0;
  for (int kt = 0; kt < kSteps; ++kt) {
    if (kt + 1 < kSteps) {
      stage(cur ^ 1, kt + 1);
      asm volatile("s_waitcnt vmcnt(%0)" :: "i"(NLOADS) : "memory");
    } else {
      asm volatile("s_waitcnt vmcnt(0)" ::: "memory");
    }
    __builtin_amdgcn_s_barrier();
    __builtin_amdgcn_sched_barrier(0);
    const u16* lA = (const u16*)(smem + cur * TILE_B);
    const u16* lB = (const u16*)(smem + cur * TILE_B + BM * 128);
#pragma unroll
    for (int kk = 0; kk < 2; ++kk) {
      const int j = kk * 4 + (lane >> 4);
      bf16x8v af[FM], bfr[FN];
#pragma unroll
      for (int fm = 0; fm < FM; ++fm) {
        int rr = wm * (BM / 2) + fm * 16 + (lane & 15);
        af[fm] = *(const bf16x8v*)(lA + rr * 64 + ((j ^ (rr & 7)) << 3));
      }
#pragma unroll
      for (int fn = 0; fn < FN; ++fn) {
        int rn = wn * 64 + fn * 16 + (lane & 15);
        bfr[fn] = *(const bf16x8v*)(lB + rn * 64 + ((j ^ (rn & 7)) << 3));
      }
      __builtin_amdgcn_s_setprio(1);
#pragma unroll
      for (int fm = 0; fm < FM; ++fm)
#pragma unroll
        for (int fn = 0; fn < FN; ++fn)
          acc[fm][fn] = __builtin_amdgcn_mfma_f32_16x16x32_bf16(
              af[fm], bfr[fn], acc[fm][fn], 0, 0, 0);
      __builtin_amdgcn_s_setprio(0);
    }
    __builtin_amdgcn_sched_barrier(0);
    __builtin_amdgcn_s_barrier();
    cur ^= 1;
  }

  const int fla = (EPI == 0) ? 0 : *fl;
  const int row0l = wm * (BM / 2);
  const int col0l = wn * 64;

  auto store_bf16 = [&](bool do_bias, bool do_gelu) {
    u16* ep = (u16*)smem;
#pragma unroll
    for (int fm = 0; fm < FM; ++fm)
#pragma unroll
      for (int fn = 0; fn < FN; ++fn)
#pragma unroll
        for (int jj = 0; jj < 4; ++jj) {
          int rl = row0l + fm * 16 + ((lane >> 4) << 2) + jj;
          int cl = col0l + fn * 16 + (lane & 15);
          float t = acc[fm][fn][jj];
          if (do_bias) t += ld_f(bias, boff + tileN + cl, fla);
          if (do_gelu) t = 0.5f * t * (1.0f + erff(t * 0.70710678118654752f));
          ep[rl * BN + cl] = f2bf(t);
        }
    __syncthreads();
    for (int rr = tid >> 4; rr < BM; rr += 16) {
      int grow = tileM + rr;
      if (grow < M)
        *(uint4*)((u16*)Cout + (size_t)grow * N + tileN + (tid & 15) * 8) =
            *(const uint4*)(ep + rr * BN + (tid & 15) * 8);
    }
  };

  auto store_f32 = [&](bool do_resid, bool do_remap_pos) {
    float* epf = (float*)smem;
#pragma unroll
    for (int p = 0; p < 2; ++p) {
      __syncthreads();
      if (wm == p) {
#pragma unroll
        for (int fm = 0; fm < FM; ++fm)
#pragma unroll
          for (int fn = 0; fn < FN; ++fn)
#pragma unroll
            for (int jj = 0; jj < 4; ++jj) {
              int rl = fm * 16 + ((lane >> 4) << 2) + jj;
              int cl = col0l + fn * 16 + (lane & 15);
              float t = acc[fm][fn][jj] + ld_f(bias, boff + tileN + cl, fla);
              if (do_remap_pos) {
                int grow_t = tileM + p * (BM / 2) + rl;
                int ll = grow_t % 49;
                t += ld_f(pos, ll * 512 + tileN + cl, fla);
              }
              epf[rl * BN + cl] = t;
            }
      }
      __syncthreads();
      for (int rr = tid >> 5; rr < BM / 2; rr += 8) {
        int grow = tileM + p * (BM / 2) + rr;
        if (grow < M) {
          f32x4 t = *(const f32x4*)(epf + rr * BN + (tid & 31) * 4);
          if (do_resid)
            t += *(const f32x4*)(resid + (size_t)grow * N + tileN + (tid & 31) * 4);
          size_t orow = grow;
          if (do_remap_pos) orow = (size_t)(grow / 49) * 126 + grow % 49;
          *(f32x4*)((float*)Cout + orow * N + tileN + (tid & 31) * 4) = t;
        }
      }
    }
  };

  if constexpr (EPI == 0) store_bf16(false, false);
  else if constexpr (EPI == 1) store_bf16(true, true);
  else if constexpr (EPI == 2) store_f32(true, false);
  else if constexpr (EPI == 3) store_f32(false, true);
  else { if (fla) store_f32(false, false); else store_bf16(true, false); }
}

// ---------------------------------------------------------------------------
// LN-fused GEMM: C = LN(X) @ Bt^T. BM=64, BN=128, K=512 (= LN width).
// Per-block two-pass row stats; A reg-staged with fused LN transform
// (issue-early loads, write-late ds_write); B via gload_lds, counted vmcnt.
// EPI 0: bf16 store. EPI 1: gelu(acc+bias) bf16. M must be % 64 == 0.
// ---------------------------------------------------------------------------
template <int EPI>
__global__ __launch_bounds__(256) void gemm_lna_kernel(
    const float* __restrict__ X, const u16* __restrict__ Bt, void* Cout,
    const void* __restrict__ bias, long boff,
    const void* __restrict__ gam, const void* __restrict__ bet, long goff,
    int M, int N, int gridM, const int* __restrict__ fl)
{
  constexpr int BM = 64, BN = 128, K = 512;
  constexpr int TILE_B = (BM + BN) * 128;        // 24 KiB / buffer
  __shared__ __align__(16) char smem[2 * TILE_B + 4096];
  float* sG = (float*)(smem + 2 * TILE_B);
  float* sBt = sG + 512;

  const int tid = threadIdx.x;
  const int lane = tid & 63, wid = tid >> 6;
  const int wm = wid >> 1, wn = wid & 1;
  const int fla = *fl;

  const int nwg = gridDim.x;
  const int q8 = nwg >> 3, r8 = nwg & 7;
  const int xcd = blockIdx.x & 7, bidx = blockIdx.x >> 3;
  const int wgid = (xcd < r8 ? xcd * (q8 + 1) : r8 * (q8 + 1) + (xcd - r8) * q8) + bidx;
  const int tileM = (wgid % gridM) * BM, tileN = (wgid / gridM) * BN;

  // ---- LN stats: thread quad (qq=tid&3) covers row rowl=tid>>2 ----
  const int rowl = tid >> 2, qq = tid & 3;
  const float* xrow = X + (size_t)(tileM + rowl) * 512 + qq * 128;
  float s = 0.f;
  for (int j = 0; j < 32; ++j) {
    f32x4 v = *(const f32x4*)(xrow + j * 4);
    s += v[0] + v[1] + v[2] + v[3];
  }
  s += __shfl_xor(s, 1, 64);
  s += __shfl_xor(s, 2, 64);
  const float mu = s * (1.0f / 512.0f);
  float q2 = 0.f;
  for (int j = 0; j < 32; ++j) {
    f32x4 v = *(const f32x4*)(xrow + j * 4);
#pragma unroll
    for (int e = 0; e < 4; ++e) { float d = v[e] - mu; q2 += d * d; }
  }
  q2 += __shfl_xor(q2, 1, 64);
  q2 += __shfl_xor(q2, 2, 64);
  const float rstd = rsqrtf(q2 * (1.0f / 512.0f) + 1e-5f);

  // gamma/beta -> LDS as f32
  sG[tid] = ld_f(gam, goff + tid, fla);
  sG[tid + 256] = ld_f(gam, goff + tid + 256, fla);
  sBt[tid] = ld_f(bet, goff + tid, fla);
  sBt[tid + 256] = ld_f(bet, goff + tid + 256, fla);

  f32x4 ax[4];
  auto loadA = [&](int kt) {
    const float* src = X + (size_t)(tileM + rowl) * 512 + kt * 64 + qq * 16;
#pragma unroll
    for (int j = 0; j < 4; ++j) ax[j] = *(const f32x4*)(src + j * 4);
  };
  auto writeA = [&](int buf, int kt) {
    u16* lA = (u16*)(smem + buf * TILE_B);
    const int kb = kt * 64 + qq * 16;
    union { u16 a[16]; uint4 v[2]; } hv;
#pragma unroll
    for (int j = 0; j < 16; ++j) {
      float xv = ax[j >> 2][j & 3];
      hv.a[j] = f2bf((xv - mu) * rstd * sG[kb + j] + sBt[kb + j]);
    }
    const int c0 = qq * 2;
    const int s0 = (c0 ^ (rowl & 7)) << 3;
    const int s1 = ((c0 + 1) ^ (rowl & 7)) << 3;
    *(uint4*)(lA + rowl * 64 + s0) = hv.v[0];
    *(uint4*)(lA + rowl * 64 + s1) = hv.v[1];
  };
  auto stageB = [&](int buf, int kt) {
    char* base = smem + buf * TILE_B + BM * 128;
#pragma unroll
    for (int it = 0; it < 4; ++it) {
      int ch = (wid * 4 + it) * 64 + lane;
      int row = ch >> 3, slot = ch & 7;
      async_copy16(Bt + (size_t)(tileN + row) * K + kt * 64 + ((slot ^ (row & 7)) << 3),
                   base + (wid * 4 + it) * 1024);
    }
  };

  f32x4 acc[2][4] = {};

  // prologue: tile 0 into buf0
  loadA(0);
  __syncthreads();             // sG/sBt visible to all (drains vm/lgkm too)
  writeA(0, 0);
  stageB(0, 0);
  asm volatile("s_waitcnt lgkmcnt(0)" ::: "memory");

  const int kSteps = K >> 6;   // 8
  int cur = 0;
  for (int kt = 0; kt < kSteps; ++kt) {
    if (kt + 1 < kSteps) {
      loadA(kt + 1);                                     // 4 vm loads (regs)
      asm volatile("s_waitcnt vmcnt(4)" ::: "memory");   // drain B(kt) glds
    } else {
      asm volatile("s_waitcnt vmcnt(0)" ::: "memory");
    }
    __builtin_amdgcn_s_barrier();
    __builtin_amdgcn_sched_barrier(0);
    const u16* lA = (const u16*)(smem + cur * TILE_B);
    const u16* lB = (const u16*)(smem + cur * TILE_B + BM * 128);
#pragma unroll
    for (int kk = 0; kk < 2; ++kk) {
      const int j = kk * 4 + (lane >> 4);
      bf16x8v af[2], bfr[4];
#pragma unroll
      for (int fm = 0; fm < 2; ++fm) {
        int rr = wm * 32 + fm * 16 + (lane & 15);
        af[fm] = *(const bf16x8v*)(lA + rr * 64 + ((j ^ (rr & 7)) << 3));
      }
#pragma unroll
      for (int fn = 0; fn < 4; ++fn) {
        int rn = wn * 64 + fn * 16 + (lane & 15);
        bfr[fn] = *(const bf16x8v*)(lB + rn * 64 + ((j ^ (rn & 7)) << 3));
      }
      __builtin_amdgcn_s_setprio(1);
#pragma unroll
      for (int fm = 0; fm < 2; ++fm)
#pragma unroll
        for (int fn = 0; fn < 4; ++fn)
          acc[fm][fn] = __builtin_amdgcn_mfma_f32_16x16x32_bf16(
              af[fm], bfr[fn], acc[fm][fn], 0, 0, 0);
      __builtin_amdgcn_s_setprio(0);
    }
    __builtin_amdgcn_sched_barrier(0);
    if (kt + 1 < kSteps) {
      writeA(cur ^ 1, kt + 1);   // compiler waits ax loads (only vm in flight)
      stageB(cur ^ 1, kt + 1);   // 4 gload_lds, stay in flight across barrier
    }
    asm volatile("s_waitcnt lgkmcnt(0)" ::: "memory");
    __builtin_amdgcn_s_barrier();
    cur ^= 1;
  }

  // epilogue: bf16 store via LDS (coalesced)
  u16* ep = (u16*)smem;
  const int row0l = wm * 32, col0l = wn * 64;
#pragma unroll
  for (int fm = 0; fm < 2; ++fm)
#pragma unroll
    for (int fn = 0; fn < 4; ++fn)
#pragma unroll
      for (int jj = 0; jj < 4; ++jj) {
        int rl = row0l + fm * 16 + ((lane >> 4) << 2) + jj;
        int cl = col0l + fn * 16 + (lane & 15);
        float t = acc[fm][fn][jj];
        if constexpr (EPI == 1) {
          t += ld_f(bias, boff + tileN + cl, fla);
          t = 0.5f * t * (1.0f + erff(t * 0.70710678118654752f));
        }
        ep[rl * BN + cl] = f2bf(t);
      }
  __syncthreads();
  for (int rr = tid >> 4; rr < BM; rr += 16) {
    int grow = tileM + rr;
    *(uint4*)((u16*)Cout + (size_t)grow * N + tileN + (tid & 15) * 8) =
        *(const uint4*)(ep + rr * BN + (tid & 15) * 8);
  }
}

// ---------------------------------------------------------------------------
// 256x256 vocab GEMM (round-9 counted-vmcnt version, unchanged).
// ---------------------------------------------------------------------------
__global__ __launch_bounds__(512) void gemm256_kernel(
    const u16* __restrict__ A, const u16* __restrict__ Bt, void* Cout,
    const void* __restrict__ bias, int M, int N, int K, int gridM,
    const int* __restrict__ fl)
{
  constexpr int BM = 256, BN = 256;
  constexpr int TILE_B = (BM + BN) * 128;
  __shared__ __align__(16) char smem[2 * TILE_B];

  const int tid = threadIdx.x;
  const int lane = tid & 63, wid = tid >> 6;
  const int wm = wid >> 2, wn = wid & 3;

  const int nwg = gridDim.x;
  const int q = nwg >> 3, r8 = nwg & 7;
  const int xcd = blockIdx.x & 7, idx = blockIdx.x >> 3;
  const int wgid = (xcd < r8 ? xcd * (q + 1) : r8 * (q + 1) + (xcd - r8) * q) + idx;
  const int tileM = (wgid % gridM) * BM, tileN = (wgid / gridM) * BN;

  f32x4 acc[8][4] = {};

  auto stage = [&](int buf, int kt) {
    char* base = smem + buf * TILE_B;
#pragma unroll
    for (int it = 0; it < 4; ++it) {
      int ch = (wid * 4 + it) * 64 + lane;
      int row = ch >> 3, slot = ch & 7;
      int grow = tileM + row; grow = grow < M ? grow : (M - 1);
      async_copy16(A + (size_t)grow * K + kt * 64 + ((slot ^ (row & 7)) << 3),
                   base + (wid * 4 + it) * 1024);
    }
#pragma unroll
    for (int it = 0; it < 4; ++it) {
      int ch = (wid * 4 + it) * 64 + lane;
      int row = ch >> 3, slot = ch & 7;
      async_copy16(Bt + (size_t)(tileN + row) * K + kt * 64 + ((slot ^ (row & 7)) << 3),
                   base + BM * 128 + (wid * 4 + it) * 1024);
    }
  };

  const int kSteps = K >> 6;
  stage(0, 0);
  int cur = 0;
  for (int kt = 0; kt < kSteps; ++kt) {
    if (kt + 1 < kSteps) {
      stage(cur ^ 1, kt + 1);
      asm volatile("s_waitcnt vmcnt(8)" ::: "memory");
    } else {
      asm volatile("s_waitcnt vmcnt(0)" ::: "memory");
    }
    __builtin_amdgcn_s_barrier();
    __builtin_amdgcn_sched_barrier(0);
    const u16* lA = (const u16*)(smem + cur * TILE_B);
    const u16* lB = (const u16*)(smem + cur * TILE_B + BM * 128);
#pragma unroll
    for (int kk = 0; kk < 2; ++kk) {
      const int j = kk * 4 + (lane >> 4);
      bf16x8v bfr[4];
#pragma unroll
      for (int fn = 0; fn < 4; ++fn) {
        int rn = wn * 64 + fn * 16 + (lane & 15);
        bfr[fn] = *(const bf16x8v*)(lB + rn * 64 + ((j ^ (rn & 7)) << 3));
      }
#pragma unroll
      for (int mh = 0; mh < 2; ++mh) {
        bf16x8v af[4];
#pragma unroll
        for (int f = 0; f < 4; ++f) {
          int rr = wm * 128 + (mh * 4 + f) * 16 + (lane & 15);
          af[f] = *(const bf16x8v*)(lA + rr * 64 + ((j ^ (rr & 7)) << 3));
        }
        __builtin_amdgcn_s_setprio(1);
#pragma unroll
        for (int f = 0; f < 4; ++f)
#pragma unroll
          for (int fn = 0; fn < 4; ++fn)
            acc[mh * 4 + f][fn] = __builtin_amdgcn_mfma_f32_16x16x32_bf16(
                af[f], bfr[fn], acc[mh * 4 + f][fn], 0, 0, 0);
        __builtin_amdgcn_s_setprio(0);
      }
    }
    __builtin_amdgcn_sched_barrier(0);
    __builtin_amdgcn_s_barrier();
    cur ^= 1;
  }

  const int fla = *fl;
  if (fla) {
    float* epf = (float*)smem;
#pragma unroll
    for (int p = 0; p < 4; ++p) {
      __syncthreads();
      if (wm == (p >> 1)) {
#pragma unroll
        for (int fq = 0; fq < 4; ++fq) {
          int fm = (p & 1) * 4 + fq;
#pragma unroll
          for (int fn = 0; fn < 4; ++fn)
#pragma unroll
            for (int jj = 0; jj < 4; ++jj) {
              int rl = fq * 16 + ((lane >> 4) << 2) + jj;
              int cl = wn * 64 + fn * 16 + (lane & 15);
              epf[rl * 256 + cl] = acc[fm][fn][jj] + ld_f(bias, tileN + cl, 1);
            }
        }
      }
      __syncthreads();
      for (int rr = tid >> 6; rr < 64; rr += 8) {
        int grow = tileM + p * 64 + rr;
        if (grow < M)
          *(f32x4*)((float*)Cout + (size_t)grow * N + tileN + lane * 4) =
              *(const f32x4*)(epf + rr * 256 + lane * 4);
      }
    }
  } else {
    u16* ep = (u16*)smem;
    __syncthreads();
#pragma unroll
    for (int fm = 0; fm < 8; ++fm)
#pragma unroll
      for (int fn = 0; fn < 4; ++fn)
#pragma unroll
        for (int jj = 0; jj < 4; ++jj) {
          int rl = wm * 128 + fm * 16 + ((lane >> 4) << 2) + jj;
          int cl = wn * 64 + fn * 16 + (lane & 15);
          ep[rl * 256 + cl] = f2bf(acc[fm][fn][jj] + ld_f(bias, tileN + cl, 0));
        }
    __syncthreads();
    for (int rr = tid >> 5; rr < 256; rr += 16) {
      int grow = tileM + rr;
      if (grow < M)
        *(uint4*)((u16*)Cout + (size_t)grow * N + tileN + (tid & 31) * 8) =
            *(const uint4*)(ep + rr * 256 + (tid & 31) * 8);
    }
  }
}

// ---------------------------------------------------------------------------
// prep_all: weight transposes + img convert + txt embed in ONE launch.
//   [0,12672)       32x32 transposes (imgw / qkv / wp / fc1 / fc2)
//   [12672,17376)   convert img_hidden -> imgbf (256 elems/block)
//   [17376,22304)   txt embed -> x
// ---------------------------------------------------------------------------
__global__ __launch_bounds__(256) void prep_all(
    const void* __restrict__ imgw, const void* __restrict__ wq,
    const void* __restrict__ wk, const void* __restrict__ wv,
    const void* __restrict__ wp, const void* __restrict__ fc1,
    const void* __restrict__ fc2, const void* __restrict__ imgh,
    const void* __restrict__ txt, const void* __restrict__ pos,
    u16* __restrict__ imgwT, u16* __restrict__ qkvT, u16* __restrict__ wpT,
    u16* __restrict__ fc1T, u16* __restrict__ fc2T,
    u16* __restrict__ imgbf, float* __restrict__ x,
    const int* __restrict__ fl)
{
  const int fla = *fl;
  const int b = blockIdx.x;
  if (b >= 12672) {
    if (b < 17376) {
      int i = (b - 12672) * 256 + threadIdx.x;
      if (i < 1204224) imgbf[i] = ld_bf(imgh, i, fla);
    } else {
      int idx = (b - 17376) * 256 + threadIdx.x;
      if (idx < 32 * 77 * 512) {
        int d = idx & 511, bt = idx >> 9;
        int t = bt % 77, bb = bt / 77;
        x[((size_t)(bb * 126 + 49 + t)) * 512 + d] =
            ld_f(txt, idx, fla) + ld_f(pos, (49 + t) * 512 + d, fla);
      }
    }
    return;
  }
  __shared__ u16 t[32][33];
  const void* in; u16* out; int R, C, cx, ry;
  size_t zi, zo;
  if (b < 384) {
    in = imgw; out = imgwT; R = 768; C = 512; zi = 0; zo = 0;
    cx = b & 15; ry = b >> 4;
  } else if (b < 3456) {
    int bb = b - 384;
    int z = bb >> 5, r2 = bb & 31;
    cx = r2 & 1; ry = r2 >> 1;
    int src = z >> 5, rem = z & 31, li = rem >> 3, hh = rem & 7;
    in = (src == 0) ? wq : (src == 1) ? wk : wv;
    out = qkvT; R = 512; C = 64;
    zi = (size_t)rem * (512 * 64);
    zo = (size_t)li * (1536 * 512) + (size_t)(src * 512 + hh * 64) * 512;
  } else if (b < 4480) {
    int bb = b - 3456;
    int z = bb >> 8, r2 = bb & 255;
    cx = r2 & 15; ry = r2 >> 4;
    in = wp; out = wpT; R = 512; C = 512;
    zi = (size_t)z * (512 * 512); zo = zi;
  } else if (b < 8576) {
    int bb = b - 4480;
    int z = bb >> 10, r2 = bb & 1023;
    cx = r2 & 63; ry = r2 >> 6;
    in = fc1; out = fc1T; R = 512; C = 2048;
    zi = (size_t)z * (512 * 2048); zo = zi;
  } else {
    int bb = b - 8576;
    int z = bb >> 10, r2 = bb & 1023;
    cx = r2 & 15; ry = r2 >> 4;
    in = fc2; out = fc2T; R = 2048; C = 512;
    zi = (size_t)z * (512 * 2048); zo = zi;
  }
  const int c0 = cx * 32, r0 = ry * 32;
  const int tx = threadIdx.x & 31, ty = threadIdx.x >> 5;
#pragma unroll
  for (int i = 0; i < 4; ++i)
    t[ty + 8 * i][tx] = ld_bf(in, zi + (size_t)(r0 + ty + 8 * i) * C + (c0 + tx), fla);
  __syncthreads();
#pragma unroll
  for (int i = 0; i < 4; ++i)
    out[zo + (size_t)(c0 + ty + 8 * i) * R + (r0 + tx)] = t[tx][ty + 8 * i];
}

// 32x32 tiled transpose (out_w at the tail).
__global__ __launch_bounds__(256) void transpose_any(
    const void* __restrict__ in, u16* __restrict__ out, int R, int C,
    const int* __restrict__ fl)
{
  const int fla = *fl;
  __shared__ u16 t[32][33];
  const size_t zo = (size_t)blockIdx.z * R * C;
  const int c0 = blockIdx.x * 32, r0 = blockIdx.y * 32;
  const int tx = threadIdx.x & 31, ty = threadIdx.x >> 5;
#pragma unroll
  for (int i = 0; i < 4; ++i)
    t[ty + 8 * i][tx] = ld_bf(in, zo + (size_t)(r0 + ty + 8 * i) * C + (c0 + tx), fla);
  __syncthreads();
#pragma unroll
  for (int i = 0; i < 4; ++i)
    out[zo + (size_t)(c0 + ty + 8 * i) * R + (r0 + tx)] = t[tx][ty + 8 * i];
}

// Attention: one block per (b, h, row-half). qkv packed [B*L][1536].
__global__ __launch_bounds__(256) void attn_kernel(
    const u16* __restrict__ qkv, const int* __restrict__ amask,
    u16* __restrict__ o)
{
  const int b = blockIdx.x, hh = blockIdx.y, half = blockIdx.z;
  __shared__ float Kf[126 * 65];
  __shared__ u16 Vh[126 * 65];
  __shared__ float P[4][128];
  __shared__ float padK[128];
  const int tid = threadIdx.x, lane = tid & 63, wid = tid >> 6;

  for (int idx = tid; idx < 126 * 64; idx += 256) {
    int m = idx >> 6, kk = idx & 63;
    size_t base = ((size_t)(b * 126 + m)) * 1536 + hh * 64 + kk;
    Kf[m * 65 + kk] = bf2f(qkv[base + 512]);
    Vh[m * 65 + kk] = qkv[base + 1024];
  }
  for (int j = tid; j < 128; j += 256) {
    float kv = 0.0f;
    if (j < 49) kv = 1.0f;
    else if (j < 126) kv = (amask[b * 77 + (j - 49)] != 0) ? 1.0f : 0.0f;
    padK[j] = kv;
  }
  __syncthreads();

  const float scale = 0.04419417382415922f;  // 512^-0.5 (full-D, faithful)
  const int lbase = half * 63;
  for (int l = lbase + wid; l < lbase + 63; l += 4) {
    float qv = bf2f(qkv[((size_t)(b * 126 + l)) * 1536 + hh * 64 + lane]);
    const int m0 = lane;
    const int m1v = lane + 64;
    const int m1 = m1v < 126 ? m1v : 125;
    const float* K0 = Kf + m0 * 65;
    const float* K1 = Kf + m1 * 65;
    float s0 = 0.f, s1 = 0.f;
#pragma unroll 8
    for (int kk = 0; kk < 64; ++kk) {
      float qs = __shfl(qv, kk, 64);
      s0 += qs * K0[kk];
      s1 += qs * K1[kk];
    }
    s0 *= scale; s1 *= scale;
    bool kp0 = (padK[m0] != 0.f) && (m0 < 49 || l < 49 || m0 <= l);
    bool kp1 = (padK[m1v] != 0.f) && (l < 49 || m1v <= l);
    float e0 = kp0 ? s0 : -1e30f;
    float e1 = kp1 ? s1 : -1e30f;
    float mx = fmaxf(e0, e1);
#pragma unroll
    for (int off = 32; off; off >>= 1) mx = fmaxf(mx, __shfl_xor(mx, off, 64));
    float p0 = kp0 ? __expf(s0 - mx) : 0.f;
    float p1 = kp1 ? __expf(s1 - mx) : 0.f;
    float sm = p0 + p1;
#pragma unroll
    for (int off = 32; off; off >>= 1) sm += __shfl_xor(sm, off, 64);
    float inv = 1.0f / sm;
    P[wid][lane] = p0 * inv;
    P[wid][lane + 64] = p1 * inv;
    float accv = 0.f;
#pragma unroll 6
    for (int m = 0; m < 126; ++m) accv += P[wid][m] * bf2f(Vh[m * 65 + lane]);
    o[((size_t)(b * 126 + l)) * 512 + hh * 64 + lane] = f2bf(accv);
  }
}

// Final LayerNorm, wave-per-row (txt rows remap).
__global__ __launch_bounds__(256) void lnf_kernel(
    const float* __restrict__ x, const void* __restrict__ gam,
    const void* __restrict__ bet, u16* __restrict__ out,
    int nrows, const int* __restrict__ fl)
{
  const int fla = *fl;
  const int lane = threadIdx.x & 63, wid = threadIdx.x >> 6;
  const int r = blockIdx.x * 4 + wid;
  if (r >= nrows) return;
  int bb = r / 77, t = r % 77;
  int srow = bb * 126 + 49 + t;
  const float* xr = x + (size_t)srow * 512 + lane * 8;
  f32x4 v0 = *(const f32x4*)xr;
  f32x4 v1 = *(const f32x4*)(xr + 4);
  float s = v0[0] + v0[1] + v0[2] + v0[3] + v1[0] + v1[1] + v1[2] + v1[3];
#pragma unroll
  for (int off = 32; off; off >>= 1) s += __shfl_xor(s, off, 64);
  const float mu = s * (1.0f / 512.0f);
  float q2 = 0.f;
#pragma unroll
  for (int j = 0; j < 4; ++j) { v0[j] -= mu; q2 += v0[j] * v0[j]; }
#pragma unroll
  for (int j = 0; j < 4; ++j) { v1[j] -= mu; q2 += v1[j] * v1[j]; }
#pragma unroll
  for (int off = 32; off; off >>= 1) q2 += __shfl_xor(q2, off, 64);
  const float inv = rsqrtf(q2 * (1.0f / 512.0f) + 1e-5f);
  union { u16 a[8]; uint4 v; } ou;
#pragma unroll
  for (int j = 0; j < 8; ++j) {
    float d = (j < 4) ? v0[j] : v1[j - 4];
    ou.a[j] = f2bf(d * inv * ld_f(gam, lane * 8 + j, fla)
                   + ld_f(bet, lane * 8 + j, fla));
  }
  *(uint4*)(out + (size_t)r * 512 + lane * 8) = ou.v;
}

// ---------------------------------------------------------------------------
extern "C" void kernel_launch(void* const* d_in, const int* in_sizes, int n_in,
                              void* d_out, int out_size, void* d_ws, size_t ws_size,
                              hipStream_t stream)
{
  (void)in_sizes; (void)n_in; (void)out_size;
  const void* img_hidden = d_in[0];
  const void* txt_emb    = d_in[1];
  const void* img_proj_w = d_in[2];
  const void* img_proj_b = d_in[3];
  const void* pos_embed  = d_in[4];
  const void* wq    = d_in[5];
  const void* wk    = d_in[6];
  const void* wv    = d_in[7];
  const void* w_proj = d_in[8];
  const void* b_proj = d_in[9];
  const void* ln1_g = d_in[10];
  const void* ln1_b = d_in[11];
  const void* ln2_g = d_in[12];
  const void* ln2_b = d_in[13];
  const void* fc1_w = d_in[14];
  const void* fc1_b = d_in[15];
  const void* fc2_w = d_in[16];
  const void* fc2_b = d_in[17];
  const void* lnf_g = d_in[18];
  const void* lnf_b = d_in[19];
  const void* out_w = d_in[20];
  const void* out_b = d_in[21];
  const int* amask  = (const int*)d_in[22];

  char* ws = (char*)d_ws;
  size_t off = 0;
  auto alloc = [&](size_t bytes) {
    void* p = ws + off; off += (bytes + 255) & ~(size_t)255; return p;
  };
  int* dflag = (int*)alloc(256);
  u16* imgbf = (u16*)alloc(1204224ull * 2);
  float* x   = (float*)alloc(4032ull * 512 * 4);
  u16* xl    = (u16*)alloc(2464ull * 512 * 2);
  const size_t uni0 = off;
  u16* imgwT = (u16*)alloc(512ull * 768 * 2);
  u16* qkvT  = (u16*)alloc(4ull * 1536 * 512 * 2);
  u16* wpT   = (u16*)alloc(4ull * 512 * 512 * 2);
  u16* fc1T  = (u16*)alloc(4ull * 2048 * 512 * 2);
  u16* fc2T  = (u16*)alloc(4ull * 512 * 2048 * 2);
  u16* qkvb  = (u16*)alloc(4032ull * 1536 * 2);
  u16* ob    = (u16*)alloc(4032ull * 512 * 2);
  u16* ff    = (u16*)alloc(4032ull * 2048 * 2);
  u16* outwT = (u16*)(ws + uni0);   // 50.6 MB, aliases dead loop buffers

  if (ws_size < off) {
    sentinel_kernel<<<dim3(16), 256, 0, stream>>>((float*)d_out);
    return;
  }

  detect_kernel<<<dim3(1), 64, 0, stream>>>(img_hidden, dflag);
  prep_all<<<dim3(22304), 256, 0, stream>>>(
      img_proj_w, wq, wk, wv, w_proj, fc1_w, fc2_w, img_hidden, txt_emb,
      pos_embed, imgwT, qkvT, wpT, fc1T, fc2T, imgbf, x, dflag);

  gemm_kernel<64, 128, 3><<<dim3(100), 256, 0, stream>>>(
      imgbf, imgwT, x, img_proj_b, 0, nullptr, pos_embed, 1568, 512, 768, 25, dflag);

  for (int i = 0; i < 4; ++i) {
    gemm_lna_kernel<0><<<dim3(756), 256, 0, stream>>>(
        x, qkvT + i * 786432, qkvb, nullptr, 0, ln1_g, ln1_b, i * 512,
        4032, 1536, 63, dflag);
    attn_kernel<<<dim3(32, 8, 2), 256, 0, stream>>>(qkvb, amask, ob);
    gemm_kernel<64, 128, 2><<<dim3(252), 256, 0, stream>>>(
        ob, wpT + i * 262144, x, b_proj, i * 512, x, nullptr, 4032, 512, 512, 63, dflag);
    gemm_lna_kernel<1><<<dim3(1008), 256, 0, stream>>>(
        x, fc1T + i * 1048576, ff, fc1_b, i * 2048, ln2_g, ln2_b, i * 512,
        4032, 2048, 63, dflag);
    gemm_kernel<64, 128, 2><<<dim3(252), 256, 0, stream>>>(
        ff, fc2T + i * 1048576, x, fc2_b, i * 512, x, nullptr, 4032, 512, 2048, 63, dflag);
  }

  lnf_kernel<<<dim3(616), 256, 0, stream>>>(x, lnf_g, lnf_b, xl, 2464, dflag);
  transpose_any<<<dim3(1544, 16, 1), 256, 0, stream>>>(out_w, outwT, 512, 49408, dflag);
  gemm256_kernel<<<dim3(1930), 512, 0, stream>>>(
      xl, outwT, d_out, out_b, 2464, 49408, 512, 10, dflag);
}

// Round 11
// 1022.005 us; speedup vs baseline: 1.1189x; 1.1189x over previous
//
#include <hip/hip_runtime.h>
#include <hip/hip_bf16.h>
#include <stdint.h>

// ---------------------------------------------------------------------------
// MMTransformer: B=32, IMG_LEN=49, TXT_LEN=77, L=126, D=512, H=8, HK=64,
// FF=2048, NB=4, IMG_DIM=768, VOCAB=49408.
// Round 11: revert LN-fusion (round-10 regression: per-N-tile stat recompute
// re-read A 12-16x). Back to round-9 GEMM structure + standalone wave-per-row
// LN. Kept merges: prep_all (transposes+convert+embed), NEW transpose_lnf
// (final LN + out_w transpose in one launch). Retained: counted-vmcnt
// pipelines, 256^2 vocab GEMM, chunk-XOR LDS swizzle, bijective XCD swizzle,
// LDS-coalesced epilogues, runtime dtype detection.
// ---------------------------------------------------------------------------

using u16 = unsigned short;
typedef __attribute__((ext_vector_type(8))) __bf16 bf16x8v;
typedef __attribute__((ext_vector_type(4))) float f32x4;

__device__ __forceinline__ float bf2f(u16 u) {
  union { unsigned int i; float f; } x; x.i = ((unsigned int)u) << 16; return x.f;
}
__device__ __forceinline__ u16 f2bf(float f) {
  union { float f; unsigned int i; } u; u.f = f;
  unsigned int r = u.i + 0x7FFFu + ((u.i >> 16) & 1u);   // RNE
  return (u16)(r >> 16);
}
__device__ __forceinline__ float ld_f(const void* p, size_t i, int fl) {
  return fl ? ((const float*)p)[i] : bf2f(((const u16*)p)[i]);
}
__device__ __forceinline__ u16 ld_bf(const void* p, size_t i, int fl) {
  return fl ? f2bf(((const float*)p)[i]) : ((const u16*)p)[i];
}

__device__ __forceinline__ void async_copy16(const void* g, void* l) {
  __builtin_amdgcn_global_load_lds(
      (__attribute__((address_space(1))) void*)(g),
      (__attribute__((address_space(3))) void*)(l), 16, 0, 0);
}

__global__ void detect_kernel(const void* __restrict__ img, int* __restrict__ flag) {
  const int lane = threadIdx.x;
  const u16* p = (const u16*)img;
  int bad = 0;
#pragma unroll
  for (int i = 0; i < 4; ++i) {
    float v = bf2f(p[lane * 4 + i]);
    float av = fabsf(v);
    if (!(av <= 1e4f) || (av != 0.0f && av < 1e-30f)) bad++;
  }
#pragma unroll
  for (int off = 32; off; off >>= 1) bad += __shfl_xor(bad, off, 64);
  if (lane == 0) flag[0] = (bad > 16) ? 1 : 0;
}

__global__ void sentinel_kernel(float* out) {
  out[blockIdx.x * 256 + threadIdx.x] = 123456.0f;
}

// ---------------------------------------------------------------------------
// Layer GEMM (bf16 A): BN=128, BK=64, counted-vmcnt 2-buffer pipeline.
// EPI 0: bf16 (no bias). EPI 1: gelu(acc+bias) bf16. EPI 2: acc+bias+resid
// f32. EPI 3: img embed f32 (+pos, row remap).
// ---------------------------------------------------------------------------
template <int BM, int BN, int EPI>
__global__ __launch_bounds__(256) void gemm_kernel(
    const u16* __restrict__ A, const u16* __restrict__ Bt, void* Cout,
    const void* __restrict__ bias, long boff, const float* resid,
    const void* __restrict__ pos, int M, int N, int K, int gridM,
    const int* __restrict__ fl)
{
  static_assert(BN == 128, "");
  static_assert(BM == 64 || BM == 128, "");
  constexpr int TILE_B = (BM + BN) * 128;
  constexpr int EPI_B = BM * BN * 2;
  constexpr int SMEM_B = (2 * TILE_B > EPI_B) ? 2 * TILE_B : EPI_B;
  __shared__ __align__(16) char smem[SMEM_B];

  const int tid = threadIdx.x;
  const int lane = tid & 63, wid = tid >> 6;
  const int wm = wid >> 1, wn = wid & 1;
  constexpr int FM = BM / 32, FN = 4;
  constexpr int ITA = BM / 32, ITB = BN / 32;
  constexpr int NLOADS = ITA + ITB;

  const int nwg = gridDim.x;
  const int q = nwg >> 3, r8 = nwg & 7;
  const int xcd = blockIdx.x & 7, idx = blockIdx.x >> 3;
  const int wgid = (xcd < r8 ? xcd * (q + 1) : r8 * (q + 1) + (xcd - r8) * q) + idx;
  const int tileM = (wgid % gridM) * BM, tileN = (wgid / gridM) * BN;

  f32x4 acc[FM][FN] = {};

  auto stage = [&](int buf, int kt) {
    char* base = smem + buf * TILE_B;
#pragma unroll
    for (int it = 0; it < ITA; ++it) {
      int ch = (wid * ITA + it) * 64 + lane;
      int row = ch >> 3, slot = ch & 7;
      int grow = tileM + row; grow = grow < M ? grow : (M - 1);
      async_copy16(A + (size_t)grow * K + kt * 64 + ((slot ^ (row & 7)) << 3),
                   base + (wid * ITA + it) * 1024);
    }
#pragma unroll
    for (int it = 0; it < ITB; ++it) {
      int ch = (wid * ITB + it) * 64 + lane;
      int row = ch >> 3, slot = ch & 7;
      async_copy16(Bt + (size_t)(tileN + row) * K + kt * 64 + ((slot ^ (row & 7)) << 3),
                   base + BM * 128 + (wid * ITB + it) * 1024);
    }
  };

  const int kSteps = K >> 6;
  stage(0, 0);
  int cur = 0;
  for (int kt = 0; kt < kSteps; ++kt) {
    if (kt + 1 < kSteps) {
      stage(cur ^ 1, kt + 1);
      asm volatile("s_waitcnt vmcnt(%0)" :: "i"(NLOADS) : "memory");
    } else {
      asm volatile("s_waitcnt vmcnt(0)" ::: "memory");
    }
    __builtin_amdgcn_s_barrier();
    __builtin_amdgcn_sched_barrier(0);
    const u16* lA = (const u16*)(smem + cur * TILE_B);
    const u16* lB = (const u16*)(smem + cur * TILE_B + BM * 128);
#pragma unroll
    for (int kk = 0; kk < 2; ++kk) {
      const int j = kk * 4 + (lane >> 4);
      bf16x8v af[FM], bfr[FN];
#pragma unroll
      for (int fm = 0; fm < FM; ++fm) {
        int rr = wm * (BM / 2) + fm * 16 + (lane & 15);
        af[fm] = *(const bf16x8v*)(lA + rr * 64 + ((j ^ (rr & 7)) << 3));
      }
#pragma unroll
      for (int fn = 0; fn < FN; ++fn) {
        int rn = wn * 64 + fn * 16 + (lane & 15);
        bfr[fn] = *(const bf16x8v*)(lB + rn * 64 + ((j ^ (rn & 7)) << 3));
      }
      __builtin_amdgcn_s_setprio(1);
#pragma unroll
      for (int fm = 0; fm < FM; ++fm)
#pragma unroll
        for (int fn = 0; fn < FN; ++fn)
          acc[fm][fn] = __builtin_amdgcn_mfma_f32_16x16x32_bf16(
              af[fm], bfr[fn], acc[fm][fn], 0, 0, 0);
      __builtin_amdgcn_s_setprio(0);
    }
    __builtin_amdgcn_sched_barrier(0);
    __builtin_amdgcn_s_barrier();
    cur ^= 1;
  }

  const int fla = (EPI == 0) ? 0 : *fl;
  const int row0l = wm * (BM / 2);
  const int col0l = wn * 64;

  auto store_bf16 = [&](bool do_bias, bool do_gelu) {
    u16* ep = (u16*)smem;
#pragma unroll
    for (int fm = 0; fm < FM; ++fm)
#pragma unroll
      for (int fn = 0; fn < FN; ++fn)
#pragma unroll
        for (int jj = 0; jj < 4; ++jj) {
          int rl = row0l + fm * 16 + ((lane >> 4) << 2) + jj;
          int cl = col0l + fn * 16 + (lane & 15);
          float t = acc[fm][fn][jj];
          if (do_bias) t += ld_f(bias, boff + tileN + cl, fla);
          if (do_gelu) t = 0.5f * t * (1.0f + erff(t * 0.70710678118654752f));
          ep[rl * BN + cl] = f2bf(t);
        }
    __syncthreads();
    for (int rr = tid >> 4; rr < BM; rr += 16) {
      int grow = tileM + rr;
      if (grow < M)
        *(uint4*)((u16*)Cout + (size_t)grow * N + tileN + (tid & 15) * 8) =
            *(const uint4*)(ep + rr * BN + (tid & 15) * 8);
    }
  };

  auto store_f32 = [&](bool do_resid, bool do_remap_pos) {
    float* epf = (float*)smem;
#pragma unroll
    for (int p = 0; p < 2; ++p) {
      __syncthreads();
      if (wm == p) {
#pragma unroll
        for (int fm = 0; fm < FM; ++fm)
#pragma unroll
          for (int fn = 0; fn < FN; ++fn)
#pragma unroll
            for (int jj = 0; jj < 4; ++jj) {
              int rl = fm * 16 + ((lane >> 4) << 2) + jj;
              int cl = col0l + fn * 16 + (lane & 15);
              float t = acc[fm][fn][jj] + ld_f(bias, boff + tileN + cl, fla);
              if (do_remap_pos) {
                int grow_t = tileM + p * (BM / 2) + rl;
                int ll = grow_t % 49;
                t += ld_f(pos, ll * 512 + tileN + cl, fla);
              }
              epf[rl * BN + cl] = t;
            }
      }
      __syncthreads();
      for (int rr = tid >> 5; rr < BM / 2; rr += 8) {
        int grow = tileM + p * (BM / 2) + rr;
        if (grow < M) {
          f32x4 t = *(const f32x4*)(epf + rr * BN + (tid & 31) * 4);
          if (do_resid)
            t += *(const f32x4*)(resid + (size_t)grow * N + tileN + (tid & 31) * 4);
          size_t orow = grow;
          if (do_remap_pos) orow = (size_t)(grow / 49) * 126 + grow % 49;
          *(f32x4*)((float*)Cout + orow * N + tileN + (tid & 31) * 4) = t;
        }
      }
    }
  };

  if constexpr (EPI == 0) store_bf16(false, false);
  else if constexpr (EPI == 1) store_bf16(true, true);
  else if constexpr (EPI == 2) store_f32(true, false);
  else if constexpr (EPI == 3) store_f32(false, true);
  else { if (fla) store_f32(false, false); else store_bf16(true, false); }
}

// ---------------------------------------------------------------------------
// 256x256 vocab GEMM: counted-vmcnt 2-buffer pipeline (round-9 version).
// ---------------------------------------------------------------------------
__global__ __launch_bounds__(512) void gemm256_kernel(
    const u16* __restrict__ A, const u16* __restrict__ Bt, void* Cout,
    const void* __restrict__ bias, int M, int N, int K, int gridM,
    const int* __restrict__ fl)
{
  constexpr int BM = 256, BN = 256;
  constexpr int TILE_B = (BM + BN) * 128;
  __shared__ __align__(16) char smem[2 * TILE_B];

  const int tid = threadIdx.x;
  const int lane = tid & 63, wid = tid >> 6;
  const int wm = wid >> 2, wn = wid & 3;

  const int nwg = gridDim.x;
  const int q = nwg >> 3, r8 = nwg & 7;
  const int xcd = blockIdx.x & 7, idx = blockIdx.x >> 3;
  const int wgid = (xcd < r8 ? xcd * (q + 1) : r8 * (q + 1) + (xcd - r8) * q) + idx;
  const int tileM = (wgid % gridM) * BM, tileN = (wgid / gridM) * BN;

  f32x4 acc[8][4] = {};

  auto stage = [&](int buf, int kt) {
    char* base = smem + buf * TILE_B;
#pragma unroll
    for (int it = 0; it < 4; ++it) {
      int ch = (wid * 4 + it) * 64 + lane;
      int row = ch >> 3, slot = ch & 7;
      int grow = tileM + row; grow = grow < M ? grow : (M - 1);
      async_copy16(A + (size_t)grow * K + kt * 64 + ((slot ^ (row & 7)) << 3),
                   base + (wid * 4 + it) * 1024);
    }
#pragma unroll
    for (int it = 0; it < 4; ++it) {
      int ch = (wid * 4 + it) * 64 + lane;
      int row = ch >> 3, slot = ch & 7;
      async_copy16(Bt + (size_t)(tileN + row) * K + kt * 64 + ((slot ^ (row & 7)) << 3),
                   base + BM * 128 + (wid * 4 + it) * 1024);
    }
  };

  const int kSteps = K >> 6;
  stage(0, 0);
  int cur = 0;
  for (int kt = 0; kt < kSteps; ++kt) {
    if (kt + 1 < kSteps) {
      stage(cur ^ 1, kt + 1);
      asm volatile("s_waitcnt vmcnt(8)" ::: "memory");
    } else {
      asm volatile("s_waitcnt vmcnt(0)" ::: "memory");
    }
    __builtin_amdgcn_s_barrier();
    __builtin_amdgcn_sched_barrier(0);
    const u16* lA = (const u16*)(smem + cur * TILE_B);
    const u16* lB = (const u16*)(smem + cur * TILE_B + BM * 128);
#pragma unroll
    for (int kk = 0; kk < 2; ++kk) {
      const int j = kk * 4 + (lane >> 4);
      bf16x8v bfr[4];
#pragma unroll
      for (int fn = 0; fn < 4; ++fn) {
        int rn = wn * 64 + fn * 16 + (lane & 15);
        bfr[fn] = *(const bf16x8v*)(lB + rn * 64 + ((j ^ (rn & 7)) << 3));
      }
#pragma unroll
      for (int mh = 0; mh < 2; ++mh) {
        bf16x8v af[4];
#pragma unroll
        for (int f = 0; f < 4; ++f) {
          int rr = wm * 128 + (mh * 4 + f) * 16 + (lane & 15);
          af[f] = *(const bf16x8v*)(lA + rr * 64 + ((j ^ (rr & 7)) << 3));
        }
        __builtin_amdgcn_s_setprio(1);
#pragma unroll
        for (int f = 0; f < 4; ++f)
#pragma unroll
          for (int fn = 0; fn < 4; ++fn)
            acc[mh * 4 + f][fn] = __builtin_amdgcn_mfma_f32_16x16x32_bf16(
                af[f], bfr[fn], acc[mh * 4 + f][fn], 0, 0, 0);
        __builtin_amdgcn_s_setprio(0);
      }
    }
    __builtin_amdgcn_sched_barrier(0);
    __builtin_amdgcn_s_barrier();
    cur ^= 1;
  }

  const int fla = *fl;
  if (fla) {
    float* epf = (float*)smem;
#pragma unroll
    for (int p = 0; p < 4; ++p) {
      __syncthreads();
      if (wm == (p >> 1)) {
#pragma unroll
        for (int fq = 0; fq < 4; ++fq) {
          int fm = (p & 1) * 4 + fq;
#pragma unroll
          for (int fn = 0; fn < 4; ++fn)
#pragma unroll
            for (int jj = 0; jj < 4; ++jj) {
              int rl = fq * 16 + ((lane >> 4) << 2) + jj;
              int cl = wn * 64 + fn * 16 + (lane & 15);
              epf[rl * 256 + cl] = acc[fm][fn][jj] + ld_f(bias, tileN + cl, 1);
            }
        }
      }
      __syncthreads();
      for (int rr = tid >> 6; rr < 64; rr += 8) {
        int grow = tileM + p * 64 + rr;
        if (grow < M)
          *(f32x4*)((float*)Cout + (size_t)grow * N + tileN + lane * 4) =
              *(const f32x4*)(epf + rr * 256 + lane * 4);
      }
    }
  } else {
    u16* ep = (u16*)smem;
    __syncthreads();
#pragma unroll
    for (int fm = 0; fm < 8; ++fm)
#pragma unroll
      for (int fn = 0; fn < 4; ++fn)
#pragma unroll
        for (int jj = 0; jj < 4; ++jj) {
          int rl = wm * 128 + fm * 16 + ((lane >> 4) << 2) + jj;
          int cl = wn * 64 + fn * 16 + (lane & 15);
          ep[rl * 256 + cl] = f2bf(acc[fm][fn][jj] + ld_f(bias, tileN + cl, 0));
        }
    __syncthreads();
    for (int rr = tid >> 5; rr < 256; rr += 16) {
      int grow = tileM + rr;
      if (grow < M)
        *(uint4*)((u16*)Cout + (size_t)grow * N + tileN + (tid & 31) * 8) =
            *(const uint4*)(ep + rr * 256 + (tid & 31) * 8);
    }
  }
}

// ---------------------------------------------------------------------------
// prep_all: weight transposes + img convert + txt embed in ONE launch.
// ---------------------------------------------------------------------------
__global__ __launch_bounds__(256) void prep_all(
    const void* __restrict__ imgw, const void* __restrict__ wq,
    const void* __restrict__ wk, const void* __restrict__ wv,
    const void* __restrict__ wp, const void* __restrict__ fc1,
    const void* __restrict__ fc2, const void* __restrict__ imgh,
    const void* __restrict__ txt, const void* __restrict__ pos,
    u16* __restrict__ imgwT, u16* __restrict__ qkvT, u16* __restrict__ wpT,
    u16* __restrict__ fc1T, u16* __restrict__ fc2T,
    u16* __restrict__ imgbf, float* __restrict__ x,
    const int* __restrict__ fl)
{
  const int fla = *fl;
  const int b = blockIdx.x;
  if (b >= 12672) {
    if (b < 17376) {
      int i = (b - 12672) * 256 + threadIdx.x;
      if (i < 1204224) imgbf[i] = ld_bf(imgh, i, fla);
    } else {
      int idx = (b - 17376) * 256 + threadIdx.x;
      if (idx < 32 * 77 * 512) {
        int d = idx & 511, bt = idx >> 9;
        int t = bt % 77, bb = bt / 77;
        x[((size_t)(bb * 126 + 49 + t)) * 512 + d] =
            ld_f(txt, idx, fla) + ld_f(pos, (49 + t) * 512 + d, fla);
      }
    }
    return;
  }
  __shared__ u16 t[32][33];
  const void* in; u16* out; int R, C, cx, ry;
  size_t zi, zo;
  if (b < 384) {
    in = imgw; out = imgwT; R = 768; C = 512; zi = 0; zo = 0;
    cx = b & 15; ry = b >> 4;
  } else if (b < 3456) {
    int bb = b - 384;
    int z = bb >> 5, r2 = bb & 31;
    cx = r2 & 1; ry = r2 >> 1;
    int src = z >> 5, rem = z & 31, li = rem >> 3, hh = rem & 7;
    in = (src == 0) ? wq : (src == 1) ? wk : wv;
    out = qkvT; R = 512; C = 64;
    zi = (size_t)rem * (512 * 64);
    zo = (size_t)li * (1536 * 512) + (size_t)(src * 512 + hh * 64) * 512;
  } else if (b < 4480) {
    int bb = b - 3456;
    int z = bb >> 8, r2 = bb & 255;
    cx = r2 & 15; ry = r2 >> 4;
    in = wp; out = wpT; R = 512; C = 512;
    zi = (size_t)z * (512 * 512); zo = zi;
  } else if (b < 8576) {
    int bb = b - 4480;
    int z = bb >> 10, r2 = bb & 1023;
    cx = r2 & 63; ry = r2 >> 6;
    in = fc1; out = fc1T; R = 512; C = 2048;
    zi = (size_t)z * (512 * 2048); zo = zi;
  } else {
    int bb = b - 8576;
    int z = bb >> 10, r2 = bb & 1023;
    cx = r2 & 15; ry = r2 >> 4;
    in = fc2; out = fc2T; R = 2048; C = 512;
    zi = (size_t)z * (512 * 2048); zo = zi;
  }
  const int c0 = cx * 32, r0 = ry * 32;
  const int tx = threadIdx.x & 31, ty = threadIdx.x >> 5;
#pragma unroll
  for (int i = 0; i < 4; ++i)
    t[ty + 8 * i][tx] = ld_bf(in, zi + (size_t)(r0 + ty + 8 * i) * C + (c0 + tx), fla);
  __syncthreads();
#pragma unroll
  for (int i = 0; i < 4; ++i)
    out[zo + (size_t)(c0 + ty + 8 * i) * R + (r0 + tx)] = t[tx][ty + 8 * i];
}

// ---------------------------------------------------------------------------
// Tail fusion: blocks [0,24704) transpose out_w 512x49408 -> outwT;
// blocks [24704,25320) final LN (wave-per-row, txt rows remap).
// ---------------------------------------------------------------------------
__global__ __launch_bounds__(256) void transpose_lnf(
    const void* __restrict__ out_w, u16* __restrict__ outwT,
    const float* __restrict__ x, const void* __restrict__ gam,
    const void* __restrict__ bet, u16* __restrict__ xl,
    const int* __restrict__ fl)
{
  const int fla = *fl;
  const int b = blockIdx.x;
  if (b >= 24704) {
    const int lane = threadIdx.x & 63, wid = threadIdx.x >> 6;
    const int r = (b - 24704) * 4 + wid;
    if (r >= 2464) return;
    int bb = r / 77, t = r % 77;
    int srow = bb * 126 + 49 + t;
    const float* xr = x + (size_t)srow * 512 + lane * 8;
    f32x4 v0 = *(const f32x4*)xr;
    f32x4 v1 = *(const f32x4*)(xr + 4);
    float s = v0[0] + v0[1] + v0[2] + v0[3] + v1[0] + v1[1] + v1[2] + v1[3];
#pragma unroll
    for (int off = 32; off; off >>= 1) s += __shfl_xor(s, off, 64);
    const float mu = s * (1.0f / 512.0f);
    float q2 = 0.f;
#pragma unroll
    for (int j = 0; j < 4; ++j) { v0[j] -= mu; q2 += v0[j] * v0[j]; }
#pragma unroll
    for (int j = 0; j < 4; ++j) { v1[j] -= mu; q2 += v1[j] * v1[j]; }
#pragma unroll
    for (int off = 32; off; off >>= 1) q2 += __shfl_xor(q2, off, 64);
    const float inv = rsqrtf(q2 * (1.0f / 512.0f) + 1e-5f);
    union { u16 a[8]; uint4 v; } ou;
#pragma unroll
    for (int j = 0; j < 8; ++j) {
      float d = (j < 4) ? v0[j] : v1[j - 4];
      ou.a[j] = f2bf(d * inv * ld_f(gam, lane * 8 + j, fla)
                     + ld_f(bet, lane * 8 + j, fla));
    }
    *(uint4*)(xl + (size_t)r * 512 + lane * 8) = ou.v;
    return;
  }
  __shared__ u16 t[32][33];
  const int cx = b % 1544, ry = b / 1544;
  const int c0 = cx * 32, r0 = ry * 32;
  const int tx = threadIdx.x & 31, ty = threadIdx.x >> 5;
#pragma unroll
  for (int i = 0; i < 4; ++i)
    t[ty + 8 * i][tx] =
        ld_bf(out_w, (size_t)(r0 + ty + 8 * i) * 49408 + (c0 + tx), fla);
  __syncthreads();
#pragma unroll
  for (int i = 0; i < 4; ++i)
    outwT[(size_t)(c0 + ty + 8 * i) * 512 + (r0 + tx)] = t[tx][ty + 8 * i];
}

// Attention: one block per (b, h, row-half). qkv packed [B*L][1536].
__global__ __launch_bounds__(256) void attn_kernel(
    const u16* __restrict__ qkv, const int* __restrict__ amask,
    u16* __restrict__ o)
{
  const int b = blockIdx.x, hh = blockIdx.y, half = blockIdx.z;
  __shared__ float Kf[126 * 65];
  __shared__ u16 Vh[126 * 65];
  __shared__ float P[4][128];
  __shared__ float padK[128];
  const int tid = threadIdx.x, lane = tid & 63, wid = tid >> 6;

  for (int idx = tid; idx < 126 * 64; idx += 256) {
    int m = idx >> 6, kk = idx & 63;
    size_t base = ((size_t)(b * 126 + m)) * 1536 + hh * 64 + kk;
    Kf[m * 65 + kk] = bf2f(qkv[base + 512]);
    Vh[m * 65 + kk] = qkv[base + 1024];
  }
  for (int j = tid; j < 128; j += 256) {
    float kv = 0.0f;
    if (j < 49) kv = 1.0f;
    else if (j < 126) kv = (amask[b * 77 + (j - 49)] != 0) ? 1.0f : 0.0f;
    padK[j] = kv;
  }
  __syncthreads();

  const float scale = 0.04419417382415922f;  // 512^-0.5 (full-D, faithful)
  const int lbase = half * 63;
  for (int l = lbase + wid; l < lbase + 63; l += 4) {
    float qv = bf2f(qkv[((size_t)(b * 126 + l)) * 1536 + hh * 64 + lane]);
    const int m0 = lane;
    const int m1v = lane + 64;
    const int m1 = m1v < 126 ? m1v : 125;
    const float* K0 = Kf + m0 * 65;
    const float* K1 = Kf + m1 * 65;
    float s0 = 0.f, s1 = 0.f;
#pragma unroll 8
    for (int kk = 0; kk < 64; ++kk) {
      float qs = __shfl(qv, kk, 64);
      s0 += qs * K0[kk];
      s1 += qs * K1[kk];
    }
    s0 *= scale; s1 *= scale;
    bool kp0 = (padK[m0] != 0.f) && (m0 < 49 || l < 49 || m0 <= l);
    bool kp1 = (padK[m1v] != 0.f) && (l < 49 || m1v <= l);
    float e0 = kp0 ? s0 : -1e30f;
    float e1 = kp1 ? s1 : -1e30f;
    float mx = fmaxf(e0, e1);
#pragma unroll
    for (int off = 32; off; off >>= 1) mx = fmaxf(mx, __shfl_xor(mx, off, 64));
    float p0 = kp0 ? __expf(s0 - mx) : 0.f;
    float p1 = kp1 ? __expf(s1 - mx) : 0.f;
    float sm = p0 + p1;
#pragma unroll
    for (int off = 32; off; off >>= 1) sm += __shfl_xor(sm, off, 64);
    float inv = 1.0f / sm;
    P[wid][lane] = p0 * inv;
    P[wid][lane + 64] = p1 * inv;
    float accv = 0.f;
#pragma unroll 6
    for (int m = 0; m < 126; ++m) accv += P[wid][m] * bf2f(Vh[m * 65 + lane]);
    o[((size_t)(b * 126 + l)) * 512 + hh * 64 + lane] = f2bf(accv);
  }
}

// LayerNorm over D=512, wave-per-row (4 rows/block, no LDS/barriers).
__global__ __launch_bounds__(256) void ln_kernel(
    const float* __restrict__ x, const void* __restrict__ gam,
    const void* __restrict__ bet, long goff, u16* __restrict__ out,
    int nrows, const int* __restrict__ fl)
{
  const int fla = *fl;
  const int lane = threadIdx.x & 63, wid = threadIdx.x >> 6;
  const int r = blockIdx.x * 4 + wid;
  if (r >= nrows) return;
  const float* xr = x + (size_t)r * 512 + lane * 8;
  f32x4 v0 = *(const f32x4*)xr;
  f32x4 v1 = *(const f32x4*)(xr + 4);
  float s = v0[0] + v0[1] + v0[2] + v0[3] + v1[0] + v1[1] + v1[2] + v1[3];
#pragma unroll
  for (int off = 32; off; off >>= 1) s += __shfl_xor(s, off, 64);
  const float mu = s * (1.0f / 512.0f);
  float q2 = 0.f;
#pragma unroll
  for (int j = 0; j < 4; ++j) { v0[j] -= mu; q2 += v0[j] * v0[j]; }
#pragma unroll
  for (int j = 0; j < 4; ++j) { v1[j] -= mu; q2 += v1[j] * v1[j]; }
#pragma unroll
  for (int off = 32; off; off >>= 1) q2 += __shfl_xor(q2, off, 64);
  const float inv = rsqrtf(q2 * (1.0f / 512.0f) + 1e-5f);
  union { u16 a[8]; uint4 v; } ou;
#pragma unroll
  for (int j = 0; j < 8; ++j) {
    float d = (j < 4) ? v0[j] : v1[j - 4];
    ou.a[j] = f2bf(d * inv * ld_f(gam, goff + lane * 8 + j, fla)
                   + ld_f(bet, goff + lane * 8 + j, fla));
  }
  *(uint4*)(out + (size_t)r * 512 + lane * 8) = ou.v;
}

// ---------------------------------------------------------------------------
extern "C" void kernel_launch(void* const* d_in, const int* in_sizes, int n_in,
                              void* d_out, int out_size, void* d_ws, size_t ws_size,
                              hipStream_t stream)
{
  (void)in_sizes; (void)n_in; (void)out_size;
  const void* img_hidden = d_in[0];
  const void* txt_emb    = d_in[1];
  const void* img_proj_w = d_in[2];
  const void* img_proj_b = d_in[3];
  const void* pos_embed  = d_in[4];
  const void* wq    = d_in[5];
  const void* wk    = d_in[6];
  const void* wv    = d_in[7];
  const void* w_proj = d_in[8];
  const void* b_proj = d_in[9];
  const void* ln1_g = d_in[10];
  const void* ln1_b = d_in[11];
  const void* ln2_g = d_in[12];
  const void* ln2_b = d_in[13];
  const void* fc1_w = d_in[14];
  const void* fc1_b = d_in[15];
  const void* fc2_w = d_in[16];
  const void* fc2_b = d_in[17];
  const void* lnf_g = d_in[18];
  const void* lnf_b = d_in[19];
  const void* out_w = d_in[20];
  const void* out_b = d_in[21];
  const int* amask  = (const int*)d_in[22];

  char* ws = (char*)d_ws;
  size_t off = 0;
  auto alloc = [&](size_t bytes) {
    void* p = ws + off; off += (bytes + 255) & ~(size_t)255; return p;
  };
  int* dflag = (int*)alloc(256);
  u16* imgbf = (u16*)alloc(1204224ull * 2);
  float* x   = (float*)alloc(4032ull * 512 * 4);
  u16* xl    = (u16*)alloc(2464ull * 512 * 2);
  const size_t uni0 = off;
  u16* imgwT = (u16*)alloc(512ull * 768 * 2);
  u16* qkvT  = (u16*)alloc(4ull * 1536 * 512 * 2);
  u16* wpT   = (u16*)alloc(4ull * 512 * 512 * 2);
  u16* fc1T  = (u16*)alloc(4ull * 2048 * 512 * 2);
  u16* fc2T  = (u16*)alloc(4ull * 512 * 2048 * 2);
  u16* h     = (u16*)alloc(4032ull * 512 * 2);
  u16* qkvb  = (u16*)alloc(4032ull * 1536 * 2);
  u16* ob    = (u16*)alloc(4032ull * 512 * 2);
  u16* ff    = (u16*)alloc(4032ull * 2048 * 2);
  u16* outwT = (u16*)(ws + uni0);   // 50.6 MB, aliases dead loop buffers

  if (ws_size < off) {
    sentinel_kernel<<<dim3(16), 256, 0, stream>>>((float*)d_out);
    return;
  }

  detect_kernel<<<dim3(1), 64, 0, stream>>>(img_hidden, dflag);
  prep_all<<<dim3(22304), 256, 0, stream>>>(
      img_proj_w, wq, wk, wv, w_proj, fc1_w, fc2_w, img_hidden, txt_emb,
      pos_embed, imgwT, qkvT, wpT, fc1T, fc2T, imgbf, x, dflag);

  gemm_kernel<64, 128, 3><<<dim3(100), 256, 0, stream>>>(
      imgbf, imgwT, x, img_proj_b, 0, nullptr, pos_embed, 1568, 512, 768, 25, dflag);

  for (int i = 0; i < 4; ++i) {
    ln_kernel<<<dim3(1008), 256, 0, stream>>>(x, ln1_g, ln1_b, i * 512, h, 4032, dflag);
    gemm_kernel<64, 128, 0><<<dim3(756), 256, 0, stream>>>(
        h, qkvT + i * 786432, qkvb, nullptr, 0, nullptr, nullptr, 4032, 1536, 512, 63, dflag);
    attn_kernel<<<dim3(32, 8, 2), 256, 0, stream>>>(qkvb, amask, ob);
    gemm_kernel<64, 128, 2><<<dim3(252), 256, 0, stream>>>(
        ob, wpT + i * 262144, x, b_proj, i * 512, x, nullptr, 4032, 512, 512, 63, dflag);
    ln_kernel<<<dim3(1008), 256, 0, stream>>>(x, ln2_g, ln2_b, i * 512, h, 4032, dflag);
    gemm_kernel<64, 128, 1><<<dim3(1008), 256, 0, stream>>>(
        h, fc1T + i * 1048576, ff, fc1_b, i * 2048, nullptr, nullptr, 4032, 2048, 512, 63, dflag);
    gemm_kernel<64, 128, 2><<<dim3(252), 256, 0, stream>>>(
        ff, fc2T + i * 1048576, x, fc2_b, i * 512, x, nullptr, 4032, 512, 2048, 63, dflag);
  }

  transpose_lnf<<<dim3(25320), 256, 0, stream>>>(
      out_w, outwT, x, lnf_g, lnf_b, xl, dflag);
  gemm256_kernel<<<dim3(1930), 512, 0, stream>>>(
      xl, outwT, d_out, out_b, 2464, 49408, 512, 10, dflag);
}

// Round 13
// 802.855 us; speedup vs baseline: 1.4243x; 1.2730x over previous
//
#include <hip/hip_runtime.h>
#include <hip/hip_bf16.h>
#include <stdint.h>

// ---------------------------------------------------------------------------
// MMTransformer: B=32, IMG_LEN=49, TXT_LEN=77, L=126, D=512, H=8, HK=64,
// FF=2048, NB=4, IMG_DIM=768, VOCAB=49408.
// Round 13: fix round-12 attn output-store bug (16-thread/row store pattern
// copied from BN=128 GEMM epilogue wrote 128 cols into a 64-wide head tile:
// cross-head race + OOB). Now 8 threads/row, exactly 64 cols. All other code
// byte-identical to round 12 (round-11 structure + MFMA attention).
// ---------------------------------------------------------------------------

using u16 = unsigned short;
typedef __attribute__((ext_vector_type(8))) __bf16 bf16x8v;
typedef __attribute__((ext_vector_type(4))) float f32x4;

__device__ __forceinline__ float bf2f(u16 u) {
  union { unsigned int i; float f; } x; x.i = ((unsigned int)u) << 16; return x.f;
}
__device__ __forceinline__ u16 f2bf(float f) {
  union { float f; unsigned int i; } u; u.f = f;
  unsigned int r = u.i + 0x7FFFu + ((u.i >> 16) & 1u);   // RNE
  return (u16)(r >> 16);
}
__device__ __forceinline__ float ld_f(const void* p, size_t i, int fl) {
  return fl ? ((const float*)p)[i] : bf2f(((const u16*)p)[i]);
}
__device__ __forceinline__ u16 ld_bf(const void* p, size_t i, int fl) {
  return fl ? f2bf(((const float*)p)[i]) : ((const u16*)p)[i];
}

__device__ __forceinline__ void async_copy16(const void* g, void* l) {
  __builtin_amdgcn_global_load_lds(
      (__attribute__((address_space(1))) void*)(g),
      (__attribute__((address_space(3))) void*)(l), 16, 0, 0);
}

__global__ void detect_kernel(const void* __restrict__ img, int* __restrict__ flag) {
  const int lane = threadIdx.x;
  const u16* p = (const u16*)img;
  int bad = 0;
#pragma unroll
  for (int i = 0; i < 4; ++i) {
    float v = bf2f(p[lane * 4 + i]);
    float av = fabsf(v);
    if (!(av <= 1e4f) || (av != 0.0f && av < 1e-30f)) bad++;
  }
#pragma unroll
  for (int off = 32; off; off >>= 1) bad += __shfl_xor(bad, off, 64);
  if (lane == 0) flag[0] = (bad > 16) ? 1 : 0;
}

__global__ void sentinel_kernel(float* out) {
  out[blockIdx.x * 256 + threadIdx.x] = 123456.0f;
}

// ---------------------------------------------------------------------------
// Layer GEMM (bf16 A): BN=128, BK=64, counted-vmcnt 2-buffer pipeline.
// ---------------------------------------------------------------------------
template <int BM, int BN, int EPI>
__global__ __launch_bounds__(256) void gemm_kernel(
    const u16* __restrict__ A, const u16* __restrict__ Bt, void* Cout,
    const void* __restrict__ bias, long boff, const float* resid,
    const void* __restrict__ pos, int M, int N, int K, int gridM,
    const int* __restrict__ fl)
{
  static_assert(BN == 128, "");
  static_assert(BM == 64 || BM == 128, "");
  constexpr int TILE_B = (BM + BN) * 128;
  constexpr int EPI_B = BM * BN * 2;
  constexpr int SMEM_B = (2 * TILE_B > EPI_B) ? 2 * TILE_B : EPI_B;
  __shared__ __align__(16) char smem[SMEM_B];

  const int tid = threadIdx.x;
  const int lane = tid & 63, wid = tid >> 6;
  const int wm = wid >> 1, wn = wid & 1;
  constexpr int FM = BM / 32, FN = 4;
  constexpr int ITA = BM / 32, ITB = BN / 32;
  constexpr int NLOADS = ITA + ITB;

  const int nwg = gridDim.x;
  const int q = nwg >> 3, r8 = nwg & 7;
  const int xcd = blockIdx.x & 7, idx = blockIdx.x >> 3;
  const int wgid = (xcd < r8 ? xcd * (q + 1) : r8 * (q + 1) + (xcd - r8) * q) + idx;
  const int tileM = (wgid % gridM) * BM, tileN = (wgid / gridM) * BN;

  f32x4 acc[FM][FN] = {};

  auto stage = [&](int buf, int kt) {
    char* base = smem + buf * TILE_B;
#pragma unroll
    for (int it = 0; it < ITA; ++it) {
      int ch = (wid * ITA + it) * 64 + lane;
      int row = ch >> 3, slot = ch & 7;
      int grow = tileM + row; grow = grow < M ? grow : (M - 1);
      async_copy16(A + (size_t)grow * K + kt * 64 + ((slot ^ (row & 7)) << 3),
                   base + (wid * ITA + it) * 1024);
    }
#pragma unroll
    for (int it = 0; it < ITB; ++it) {
      int ch = (wid * ITB + it) * 64 + lane;
      int row = ch >> 3, slot = ch & 7;
      async_copy16(Bt + (size_t)(tileN + row) * K + kt * 64 + ((slot ^ (row & 7)) << 3),
                   base + BM * 128 + (wid * ITB + it) * 1024);
    }
  };

  const int kSteps = K >> 6;
  stage(0, 0);
  int cur = 0;
  for (int kt = 0; kt < kSteps; ++kt) {
    if (kt + 1 < kSteps) {
      stage(cur ^ 1, kt + 1);
      asm volatile("s_waitcnt vmcnt(%0)" :: "i"(NLOADS) : "memory");
    } else {
      asm volatile("s_waitcnt vmcnt(0)" ::: "memory");
    }
    __builtin_amdgcn_s_barrier();
    __builtin_amdgcn_sched_barrier(0);
    const u16* lA = (const u16*)(smem + cur * TILE_B);
    const u16* lB = (const u16*)(smem + cur * TILE_B + BM * 128);
#pragma unroll
    for (int kk = 0; kk < 2; ++kk) {
      const int j = kk * 4 + (lane >> 4);
      bf16x8v af[FM], bfr[FN];
#pragma unroll
      for (int fm = 0; fm < FM; ++fm) {
        int rr = wm * (BM / 2) + fm * 16 + (lane & 15);
        af[fm] = *(const bf16x8v*)(lA + rr * 64 + ((j ^ (rr & 7)) << 3));
      }
#pragma unroll
      for (int fn = 0; fn < FN; ++fn) {
        int rn = wn * 64 + fn * 16 + (lane & 15);
        bfr[fn] = *(const bf16x8v*)(lB + rn * 64 + ((j ^ (rn & 7)) << 3));
      }
      __builtin_amdgcn_s_setprio(1);
#pragma unroll
      for (int fm = 0; fm < FM; ++fm)
#pragma unroll
        for (int fn = 0; fn < FN; ++fn)
          acc[fm][fn] = __builtin_amdgcn_mfma_f32_16x16x32_bf16(
              af[fm], bfr[fn], acc[fm][fn], 0, 0, 0);
      __builtin_amdgcn_s_setprio(0);
    }
    __builtin_amdgcn_sched_barrier(0);
    __builtin_amdgcn_s_barrier();
    cur ^= 1;
  }

  const int fla = (EPI == 0) ? 0 : *fl;
  const int row0l = wm * (BM / 2);
  const int col0l = wn * 64;

  auto store_bf16 = [&](bool do_bias, bool do_gelu) {
    u16* ep = (u16*)smem;
#pragma unroll
    for (int fm = 0; fm < FM; ++fm)
#pragma unroll
      for (int fn = 0; fn < FN; ++fn)
#pragma unroll
        for (int jj = 0; jj < 4; ++jj) {
          int rl = row0l + fm * 16 + ((lane >> 4) << 2) + jj;
          int cl = col0l + fn * 16 + (lane & 15);
          float t = acc[fm][fn][jj];
          if (do_bias) t += ld_f(bias, boff + tileN + cl, fla);
          if (do_gelu) t = 0.5f * t * (1.0f + erff(t * 0.70710678118654752f));
          ep[rl * BN + cl] = f2bf(t);
        }
    __syncthreads();
    for (int rr = tid >> 4; rr < BM; rr += 16) {
      int grow = tileM + rr;
      if (grow < M)
        *(uint4*)((u16*)Cout + (size_t)grow * N + tileN + (tid & 15) * 8) =
            *(const uint4*)(ep + rr * BN + (tid & 15) * 8);
    }
  };

  auto store_f32 = [&](bool do_resid, bool do_remap_pos) {
    float* epf = (float*)smem;
#pragma unroll
    for (int p = 0; p < 2; ++p) {
      __syncthreads();
      if (wm == p) {
#pragma unroll
        for (int fm = 0; fm < FM; ++fm)
#pragma unroll
          for (int fn = 0; fn < FN; ++fn)
#pragma unroll
            for (int jj = 0; jj < 4; ++jj) {
              int rl = fm * 16 + ((lane >> 4) << 2) + jj;
              int cl = col0l + fn * 16 + (lane & 15);
              float t = acc[fm][fn][jj] + ld_f(bias, boff + tileN + cl, fla);
              if (do_remap_pos) {
                int grow_t = tileM + p * (BM / 2) + rl;
                int ll = grow_t % 49;
                t += ld_f(pos, ll * 512 + tileN + cl, fla);
              }
              epf[rl * BN + cl] = t;
            }
      }
      __syncthreads();
      for (int rr = tid >> 5; rr < BM / 2; rr += 8) {
        int grow = tileM + p * (BM / 2) + rr;
        if (grow < M) {
          f32x4 t = *(const f32x4*)(epf + rr * BN + (tid & 31) * 4);
          if (do_resid)
            t += *(const f32x4*)(resid + (size_t)grow * N + tileN + (tid & 31) * 4);
          size_t orow = grow;
          if (do_remap_pos) orow = (size_t)(grow / 49) * 126 + grow % 49;
          *(f32x4*)((float*)Cout + orow * N + tileN + (tid & 31) * 4) = t;
        }
      }
    }
  };

  if constexpr (EPI == 0) store_bf16(false, false);
  else if constexpr (EPI == 1) store_bf16(true, true);
  else if constexpr (EPI == 2) store_f32(true, false);
  else if constexpr (EPI == 3) store_f32(false, true);
  else { if (fla) store_f32(false, false); else store_bf16(true, false); }
}

// ---------------------------------------------------------------------------
// 256x256 vocab GEMM: counted-vmcnt 2-buffer pipeline.
// ---------------------------------------------------------------------------
__global__ __launch_bounds__(512) void gemm256_kernel(
    const u16* __restrict__ A, const u16* __restrict__ Bt, void* Cout,
    const void* __restrict__ bias, int M, int N, int K, int gridM,
    const int* __restrict__ fl)
{
  constexpr int BM = 256, BN = 256;
  constexpr int TILE_B = (BM + BN) * 128;
  __shared__ __align__(16) char smem[2 * TILE_B];

  const int tid = threadIdx.x;
  const int lane = tid & 63, wid = tid >> 6;
  const int wm = wid >> 2, wn = wid & 3;

  const int nwg = gridDim.x;
  const int q = nwg >> 3, r8 = nwg & 7;
  const int xcd = blockIdx.x & 7, idx = blockIdx.x >> 3;
  const int wgid = (xcd < r8 ? xcd * (q + 1) : r8 * (q + 1) + (xcd - r8) * q) + idx;
  const int tileM = (wgid % gridM) * BM, tileN = (wgid / gridM) * BN;

  f32x4 acc[8][4] = {};

  auto stage = [&](int buf, int kt) {
    char* base = smem + buf * TILE_B;
#pragma unroll
    for (int it = 0; it < 4; ++it) {
      int ch = (wid * 4 + it) * 64 + lane;
      int row = ch >> 3, slot = ch & 7;
      int grow = tileM + row; grow = grow < M ? grow : (M - 1);
      async_copy16(A + (size_t)grow * K + kt * 64 + ((slot ^ (row & 7)) << 3),
                   base + (wid * 4 + it) * 1024);
    }
#pragma unroll
    for (int it = 0; it < 4; ++it) {
      int ch = (wid * 4 + it) * 64 + lane;
      int row = ch >> 3, slot = ch & 7;
      async_copy16(Bt + (size_t)(tileN + row) * K + kt * 64 + ((slot ^ (row & 7)) << 3),
                   base + BM * 128 + (wid * 4 + it) * 1024);
    }
  };

  const int kSteps = K >> 6;
  stage(0, 0);
  int cur = 0;
  for (int kt = 0; kt < kSteps; ++kt) {
    if (kt + 1 < kSteps) {
      stage(cur ^ 1, kt + 1);
      asm volatile("s_waitcnt vmcnt(8)" ::: "memory");
    } else {
      asm volatile("s_waitcnt vmcnt(0)" ::: "memory");
    }
    __builtin_amdgcn_s_barrier();
    __builtin_amdgcn_sched_barrier(0);
    const u16* lA = (const u16*)(smem + cur * TILE_B);
    const u16* lB = (const u16*)(smem + cur * TILE_B + BM * 128);
#pragma unroll
    for (int kk = 0; kk < 2; ++kk) {
      const int j = kk * 4 + (lane >> 4);
      bf16x8v bfr[4];
#pragma unroll
      for (int fn = 0; fn < 4; ++fn) {
        int rn = wn * 64 + fn * 16 + (lane & 15);
        bfr[fn] = *(const bf16x8v*)(lB + rn * 64 + ((j ^ (rn & 7)) << 3));
      }
#pragma unroll
      for (int mh = 0; mh < 2; ++mh) {
        bf16x8v af[4];
#pragma unroll
        for (int f = 0; f < 4; ++f) {
          int rr = wm * 128 + (mh * 4 + f) * 16 + (lane & 15);
          af[f] = *(const bf16x8v*)(lA + rr * 64 + ((j ^ (rr & 7)) << 3));
        }
        __builtin_amdgcn_s_setprio(1);
#pragma unroll
        for (int f = 0; f < 4; ++f)
#pragma unroll
          for (int fn = 0; fn < 4; ++fn)
            acc[mh * 4 + f][fn] = __builtin_amdgcn_mfma_f32_16x16x32_bf16(
                af[f], bfr[fn], acc[mh * 4 + f][fn], 0, 0, 0);
        __builtin_amdgcn_s_setprio(0);
      }
    }
    __builtin_amdgcn_sched_barrier(0);
    __builtin_amdgcn_s_barrier();
    cur ^= 1;
  }

  const int fla = *fl;
  if (fla) {
    float* epf = (float*)smem;
#pragma unroll
    for (int p = 0; p < 4; ++p) {
      __syncthreads();
      if (wm == (p >> 1)) {
#pragma unroll
        for (int fq = 0; fq < 4; ++fq) {
          int fm = (p & 1) * 4 + fq;
#pragma unroll
          for (int fn = 0; fn < 4; ++fn)
#pragma unroll
            for (int jj = 0; jj < 4; ++jj) {
              int rl = fq * 16 + ((lane >> 4) << 2) + jj;
              int cl = wn * 64 + fn * 16 + (lane & 15);
              epf[rl * 256 + cl] = acc[fm][fn][jj] + ld_f(bias, tileN + cl, 1);
            }
        }
      }
      __syncthreads();
      for (int rr = tid >> 6; rr < 64; rr += 8) {
        int grow = tileM + p * 64 + rr;
        if (grow < M)
          *(f32x4*)((float*)Cout + (size_t)grow * N + tileN + lane * 4) =
              *(const f32x4*)(epf + rr * 256 + lane * 4);
      }
    }
  } else {
    u16* ep = (u16*)smem;
    __syncthreads();
#pragma unroll
    for (int fm = 0; fm < 8; ++fm)
#pragma unroll
      for (int fn = 0; fn < 4; ++fn)
#pragma unroll
        for (int jj = 0; jj < 4; ++jj) {
          int rl = wm * 128 + fm * 16 + ((lane >> 4) << 2) + jj;
          int cl = wn * 64 + fn * 16 + (lane & 15);
          ep[rl * 256 + cl] = f2bf(acc[fm][fn][jj] + ld_f(bias, tileN + cl, 0));
        }
    __syncthreads();
    for (int rr = tid >> 5; rr < 256; rr += 16) {
      int grow = tileM + rr;
      if (grow < M)
        *(uint4*)((u16*)Cout + (size_t)grow * N + tileN + (tid & 31) * 8) =
            *(const uint4*)(ep + rr * 256 + (tid & 31) * 8);
    }
  }
}

// ---------------------------------------------------------------------------
// prep_all: weight transposes + img convert + txt embed in ONE launch.
// ---------------------------------------------------------------------------
__global__ __launch_bounds__(256) void prep_all(
    const void* __restrict__ imgw, const void* __restrict__ wq,
    const void* __restrict__ wk, const void* __restrict__ wv,
    const void* __restrict__ wp, const void* __restrict__ fc1,
    const void* __restrict__ fc2, const void* __restrict__ imgh,
    const void* __restrict__ txt, const void* __restrict__ pos,
    u16* __restrict__ imgwT, u16* __restrict__ qkvT, u16* __restrict__ wpT,
    u16* __restrict__ fc1T, u16* __restrict__ fc2T,
    u16* __restrict__ imgbf, float* __restrict__ x,
    const int* __restrict__ fl)
{
  const int fla = *fl;
  const int b = blockIdx.x;
  if (b >= 12672) {
    if (b < 17376) {
      int i = (b - 12672) * 256 + threadIdx.x;
      if (i < 1204224) imgbf[i] = ld_bf(imgh, i, fla);
    } else {
      int idx = (b - 17376) * 256 + threadIdx.x;
      if (idx < 32 * 77 * 512) {
        int d = idx & 511, bt = idx >> 9;
        int t = bt % 77, bb = bt / 77;
        x[((size_t)(bb * 126 + 49 + t)) * 512 + d] =
            ld_f(txt, idx, fla) + ld_f(pos, (49 + t) * 512 + d, fla);
      }
    }
    return;
  }
  __shared__ u16 t[32][33];
  const void* in; u16* out; int R, C, cx, ry;
  size_t zi, zo;
  if (b < 384) {
    in = imgw; out = imgwT; R = 768; C = 512; zi = 0; zo = 0;
    cx = b & 15; ry = b >> 4;
  } else if (b < 3456) {
    int bb = b - 384;
    int z = bb >> 5, r2 = bb & 31;
    cx = r2 & 1; ry = r2 >> 1;
    int src = z >> 5, rem = z & 31, li = rem >> 3, hh = rem & 7;
    in = (src == 0) ? wq : (src == 1) ? wk : wv;
    out = qkvT; R = 512; C = 64;
    zi = (size_t)rem * (512 * 64);
    zo = (size_t)li * (1536 * 512) + (size_t)(src * 512 + hh * 64) * 512;
  } else if (b < 4480) {
    int bb = b - 3456;
    int z = bb >> 8, r2 = bb & 255;
    cx = r2 & 15; ry = r2 >> 4;
    in = wp; out = wpT; R = 512; C = 512;
    zi = (size_t)z * (512 * 512); zo = zi;
  } else if (b < 8576) {
    int bb = b - 4480;
    int z = bb >> 10, r2 = bb & 1023;
    cx = r2 & 63; ry = r2 >> 6;
    in = fc1; out = fc1T; R = 512; C = 2048;
    zi = (size_t)z * (512 * 2048); zo = zi;
  } else {
    int bb = b - 8576;
    int z = bb >> 10, r2 = bb & 1023;
    cx = r2 & 15; ry = r2 >> 4;
    in = fc2; out = fc2T; R = 2048; C = 512;
    zi = (size_t)z * (512 * 2048); zo = zi;
  }
  const int c0 = cx * 32, r0 = ry * 32;
  const int tx = threadIdx.x & 31, ty = threadIdx.x >> 5;
#pragma unroll
  for (int i = 0; i < 4; ++i)
    t[ty + 8 * i][tx] = ld_bf(in, zi + (size_t)(r0 + ty + 8 * i) * C + (c0 + tx), fla);
  __syncthreads();
#pragma unroll
  for (int i = 0; i < 4; ++i)
    out[zo + (size_t)(c0 + ty + 8 * i) * R + (r0 + tx)] = t[tx][ty + 8 * i];
}

// ---------------------------------------------------------------------------
// Tail fusion: out_w transpose + final LN in one launch.
// ---------------------------------------------------------------------------
__global__ __launch_bounds__(256) void transpose_lnf(
    const void* __restrict__ out_w, u16* __restrict__ outwT,
    const float* __restrict__ x, const void* __restrict__ gam,
    const void* __restrict__ bet, u16* __restrict__ xl,
    const int* __restrict__ fl)
{
  const int fla = *fl;
  const int b = blockIdx.x;
  if (b >= 24704) {
    const int lane = threadIdx.x & 63, wid = threadIdx.x >> 6;
    const int r = (b - 24704) * 4 + wid;
    if (r >= 2464) return;
    int bb = r / 77, t = r % 77;
    int srow = bb * 126 + 49 + t;
    const float* xr = x + (size_t)srow * 512 + lane * 8;
    f32x4 v0 = *(const f32x4*)xr;
    f32x4 v1 = *(const f32x4*)(xr + 4);
    float s = v0[0] + v0[1] + v0[2] + v0[3] + v1[0] + v1[1] + v1[2] + v1[3];
#pragma unroll
    for (int off = 32; off; off >>= 1) s += __shfl_xor(s, off, 64);
    const float mu = s * (1.0f / 512.0f);
    float q2 = 0.f;
#pragma unroll
    for (int j = 0; j < 4; ++j) { v0[j] -= mu; q2 += v0[j] * v0[j]; }
#pragma unroll
    for (int j = 0; j < 4; ++j) { v1[j] -= mu; q2 += v1[j] * v1[j]; }
#pragma unroll
    for (int off = 32; off; off >>= 1) q2 += __shfl_xor(q2, off, 64);
    const float inv = rsqrtf(q2 * (1.0f / 512.0f) + 1e-5f);
    union { u16 a[8]; uint4 v; } ou;
#pragma unroll
    for (int j = 0; j < 8; ++j) {
      float d = (j < 4) ? v0[j] : v1[j - 4];
      ou.a[j] = f2bf(d * inv * ld_f(gam, lane * 8 + j, fla)
                     + ld_f(bet, lane * 8 + j, fla));
    }
    *(uint4*)(xl + (size_t)r * 512 + lane * 8) = ou.v;
    return;
  }
  __shared__ u16 t[32][33];
  const int cx = b % 1544, ry = b / 1544;
  const int c0 = cx * 32, r0 = ry * 32;
  const int tx = threadIdx.x & 31, ty = threadIdx.x >> 5;
#pragma unroll
  for (int i = 0; i < 4; ++i)
    t[ty + 8 * i][tx] =
        ld_bf(out_w, (size_t)(r0 + ty + 8 * i) * 49408 + (c0 + tx), fla);
  __syncthreads();
#pragma unroll
  for (int i = 0; i < 4; ++i)
    outwT[(size_t)(c0 + ty + 8 * i) * 512 + (r0 + tx)] = t[tx][ty + 8 * i];
}

// ---------------------------------------------------------------------------
// MFMA attention: one block per (b,h), 256 threads / 4 waves.
// ---------------------------------------------------------------------------
__global__ __launch_bounds__(256) void attn_mfma_kernel(
    const u16* __restrict__ qkv, const int* __restrict__ amask,
    u16* __restrict__ o)
{
  const int b = blockIdx.x, hh = blockIdx.y;
  __shared__ __align__(16) u16 Qs[128 * 64];
  __shared__ __align__(16) u16 Ks[128 * 64];
  __shared__ __align__(16) u16 Vt[64 * 136];
  __shared__ float Sf[128 * 129];
  __shared__ __align__(16) u16 Ps[128 * 128];
  __shared__ float padK[128];
  const int tid = threadIdx.x, lane = tid & 63, wid = tid >> 6;

  // stage Q,K: chunk-XOR pre-swizzled source, linear LDS (GEMM pattern)
  for (int ch = tid; ch < 1024; ch += 256) {
    int row = ch >> 3, slot = ch & 7;
    int gm = row < 126 ? row : 125;                  // dup row (finite pad)
    size_t base = ((size_t)(b * 126 + gm)) * 1536 + hh * 64;
    int gslot = slot ^ (row & 7);
    *(uint4*)(Qs + row * 64 + slot * 8) = *(const uint4*)(qkv + base + gslot * 8);
    *(uint4*)(Ks + row * 64 + slot * 8) = *(const uint4*)(qkv + base + 512 + gslot * 8);
  }
  // stage V^T: Vt[hk][m] = V[m][hk]
  for (int m = wid; m < 126; m += 4) {
    size_t base = ((size_t)(b * 126 + m)) * 1536 + hh * 64 + 1024;
    Vt[lane * 136 + m] = qkv[base + lane];
  }
  if (wid == 0) { Vt[lane * 136 + 126] = 0; Vt[lane * 136 + 127] = 0; }
  for (int j = tid; j < 128; j += 256) {
    float kv = 0.0f;
    if (j < 49) kv = 1.0f;
    else if (j < 126) kv = (amask[b * 77 + (j - 49)] != 0) ? 1.0f : 0.0f;
    padK[j] = kv;
  }
  __syncthreads();

  // QK^T: wave owns row-frags {2*wid, 2*wid+1} x col-frags 0..7
  f32x4 accS[2][8] = {};
#pragma unroll
  for (int ks = 0; ks < 2; ++ks) {
    const int j = ks * 4 + (lane >> 4);
    bf16x8v qf[2], kf[8];
#pragma unroll
    for (int fr = 0; fr < 2; ++fr) {
      int rr = (wid * 2 + fr) * 16 + (lane & 15);
      qf[fr] = *(const bf16x8v*)(Qs + rr * 64 + ((j ^ (rr & 7)) << 3));
    }
#pragma unroll
    for (int fc = 0; fc < 8; ++fc) {
      int rn = fc * 16 + (lane & 15);
      kf[fc] = *(const bf16x8v*)(Ks + rn * 64 + ((j ^ (rn & 7)) << 3));
    }
#pragma unroll
    for (int fr = 0; fr < 2; ++fr)
#pragma unroll
      for (int fc = 0; fc < 8; ++fc)
        accS[fr][fc] = __builtin_amdgcn_mfma_f32_16x16x32_bf16(
            qf[fr], kf[fc], accS[fr][fc], 0, 0, 0);
  }
#pragma unroll
  for (int fr = 0; fr < 2; ++fr)
#pragma unroll
    for (int fc = 0; fc < 8; ++fc)
#pragma unroll
      for (int jj = 0; jj < 4; ++jj) {
        int row = (wid * 2 + fr) * 16 + ((lane >> 4) << 2) + jj;
        int col = fc * 16 + (lane & 15);
        Sf[row * 129 + col] = accS[fr][fc][jj];
      }
  __syncthreads();

  // masked softmax, wave per row; write P bf16 with chunk-XOR swizzle
  const float scale = 0.04419417382415922f;  // 512^-0.5 (full-D, faithful)
  for (int r = wid; r < 128; r += 4) {
    const int m0 = lane, m1 = lane + 64;
    float s0 = Sf[r * 129 + m0] * scale;
    float s1 = Sf[r * 129 + m1] * scale;
    bool kp0 = (padK[m0] != 0.f) && (m0 < 49 || r < 49 || m0 <= r);
    bool kp1 = (padK[m1] != 0.f) && (r < 49 || m1 <= r);
    float e0 = kp0 ? s0 : -1e30f;
    float e1 = kp1 ? s1 : -1e30f;
    float mx = fmaxf(e0, e1);
#pragma unroll
    for (int off = 32; off; off >>= 1) mx = fmaxf(mx, __shfl_xor(mx, off, 64));
    float p0 = kp0 ? __expf(s0 - mx) : 0.f;
    float p1 = kp1 ? __expf(s1 - mx) : 0.f;
    float sm = p0 + p1;
#pragma unroll
    for (int off = 32; off; off >>= 1) sm += __shfl_xor(sm, off, 64);
    float inv = 1.0f / sm;
    Ps[r * 128 + (((m0 >> 3) ^ (r & 7)) << 3) + (m0 & 7)] = f2bf(p0 * inv);
    Ps[r * 128 + (((m1 >> 3) ^ (r & 7)) << 3) + (m1 & 7)] = f2bf(p1 * inv);
  }
  __syncthreads();

  // O = P @ V: wave owns row-frags {2*wid, 2*wid+1} x col-frags 0..3 (hk)
  f32x4 accO[2][4] = {};
#pragma unroll
  for (int ks = 0; ks < 4; ++ks) {
    const int j = ks * 4 + (lane >> 4);              // k-chunk 0..15
    bf16x8v pf[2], vf[4];
#pragma unroll
    for (int fr = 0; fr < 2; ++fr) {
      int rr = (wid * 2 + fr) * 16 + (lane & 15);
      pf[fr] = *(const bf16x8v*)(Ps + rr * 128 + ((j ^ (rr & 7)) << 3));
    }
#pragma unroll
    for (int fc = 0; fc < 4; ++fc) {
      int rn = fc * 16 + (lane & 15);                // hk row of Vt
      vf[fc] = *(const bf16x8v*)(Vt + rn * 136 + (j << 3));
    }
#pragma unroll
    for (int fr = 0; fr < 2; ++fr)
#pragma unroll
      for (int fc = 0; fc < 4; ++fc)
        accO[fr][fc] = __builtin_amdgcn_mfma_f32_16x16x32_bf16(
            pf[fr], vf[fc], accO[fr][fc], 0, 0, 0);
  }

  // stage O into LDS (reuse Qs region) and write coalesced (64-wide tile:
  // 8 threads x 8 u16 per row — round-12 bug was 16 threads = 128 cols).
  u16* Ol = Qs;                                       // [128][64]
  __syncthreads();
#pragma unroll
  for (int fr = 0; fr < 2; ++fr)
#pragma unroll
    for (int fc = 0; fc < 4; ++fc)
#pragma unroll
      for (int jj = 0; jj < 4; ++jj) {
        int row = (wid * 2 + fr) * 16 + ((lane >> 4) << 2) + jj;
        int col = fc * 16 + (lane & 15);
        Ol[row * 64 + col] = f2bf(accO[fr][fc][jj]);
      }
  __syncthreads();
  for (int r = tid >> 3; r < 126; r += 32) {
    *(uint4*)(o + ((size_t)(b * 126 + r)) * 512 + hh * 64 + (tid & 7) * 8) =
        *(const uint4*)(Ol + r * 64 + (tid & 7) * 8);
  }
}

// LayerNorm over D=512, wave-per-row (4 rows/block, no LDS/barriers).
__global__ __launch_bounds__(256) void ln_kernel(
    const float* __restrict__ x, const void* __restrict__ gam,
    const void* __restrict__ bet, long goff, u16* __restrict__ out,
    int nrows, const int* __restrict__ fl)
{
  const int fla = *fl;
  const int lane = threadIdx.x & 63, wid = threadIdx.x >> 6;
  const int r = blockIdx.x * 4 + wid;
  if (r >= nrows) return;
  const float* xr = x + (size_t)r * 512 + lane * 8;
  f32x4 v0 = *(const f32x4*)xr;
  f32x4 v1 = *(const f32x4*)(xr + 4);
  float s = v0[0] + v0[1] + v0[2] + v0[3] + v1[0] + v1[1] + v1[2] + v1[3];
#pragma unroll
  for (int off = 32; off; off >>= 1) s += __shfl_xor(s, off, 64);
  const float mu = s * (1.0f / 512.0f);
  float q2 = 0.f;
#pragma unroll
  for (int j = 0; j < 4; ++j) { v0[j] -= mu; q2 += v0[j] * v0[j]; }
#pragma unroll
  for (int j = 0; j < 4; ++j) { v1[j] -= mu; q2 += v1[j] * v1[j]; }
#pragma unroll
  for (int off = 32; off; off >>= 1) q2 += __shfl_xor(q2, off, 64);
  const float inv = rsqrtf(q2 * (1.0f / 512.0f) + 1e-5f);
  union { u16 a[8]; uint4 v; } ou;
#pragma unroll
  for (int j = 0; j < 8; ++j) {
    float d = (j < 4) ? v0[j] : v1[j - 4];
    ou.a[j] = f2bf(d * inv * ld_f(gam, goff + lane * 8 + j, fla)
                   + ld_f(bet, goff + lane * 8 + j, fla));
  }
  *(uint4*)(out + (size_t)r * 512 + lane * 8) = ou.v;
}

// ---------------------------------------------------------------------------
extern "C" void kernel_launch(void* const* d_in, const int* in_sizes, int n_in,
                              void* d_out, int out_size, void* d_ws, size_t ws_size,
                              hipStream_t stream)
{
  (void)in_sizes; (void)n_in; (void)out_size;
  const void* img_hidden = d_in[0];
  const void* txt_emb    = d_in[1];
  const void* img_proj_w = d_in[2];
  const void* img_proj_b = d_in[3];
  const void* pos_embed  = d_in[4];
  const void* wq    = d_in[5];
  const void* wk    = d_in[6];
  const void* wv    = d_in[7];
  const void* w_proj = d_in[8];
  const void* b_proj = d_in[9];
  const void* ln1_g = d_in[10];
  const void* ln1_b = d_in[11];
  const void* ln2_g = d_in[12];
  const void* ln2_b = d_in[13];
  const void* fc1_w = d_in[14];
  const void* fc1_b = d_in[15];
  const void* fc2_w = d_in[16];
  const void* fc2_b = d_in[17];
  const void* lnf_g = d_in[18];
  const void* lnf_b = d_in[19];
  const void* out_w = d_in[20];
  const void* out_b = d_in[21];
  const int* amask  = (const int*)d_in[22];

  char* ws = (char*)d_ws;
  size_t off = 0;
  auto alloc = [&](size_t bytes) {
    void* p = ws + off; off += (bytes + 255) & ~(size_t)255; return p;
  };
  int* dflag = (int*)alloc(256);
  u16* imgbf = (u16*)alloc(1204224ull * 2);
  float* x   = (float*)alloc(4032ull * 512 * 4);
  u16* xl    = (u16*)alloc(2464ull * 512 * 2);
  const size_t uni0 = off;
  u16* imgwT = (u16*)alloc(512ull * 768 * 2);
  u16* qkvT  = (u16*)alloc(4ull * 1536 * 512 * 2);
  u16* wpT   = (u16*)alloc(4ull * 512 * 512 * 2);
  u16* fc1T  = (u16*)alloc(4ull * 2048 * 512 * 2);
  u16* fc2T  = (u16*)alloc(4ull * 512 * 2048 * 2);
  u16* h     = (u16*)alloc(4032ull * 512 * 2);
  u16* qkvb  = (u16*)alloc(4032ull * 1536 * 2);
  u16* ob    = (u16*)alloc(4032ull * 512 * 2);
  u16* ff    = (u16*)alloc(4032ull * 2048 * 2);
  u16* outwT = (u16*)(ws + uni0);   // 50.6 MB, aliases dead loop buffers

  if (ws_size < off) {
    sentinel_kernel<<<dim3(16), 256, 0, stream>>>((float*)d_out);
    return;
  }

  detect_kernel<<<dim3(1), 64, 0, stream>>>(img_hidden, dflag);
  prep_all<<<dim3(22304), 256, 0, stream>>>(
      img_proj_w, wq, wk, wv, w_proj, fc1_w, fc2_w, img_hidden, txt_emb,
      pos_embed, imgwT, qkvT, wpT, fc1T, fc2T, imgbf, x, dflag);

  gemm_kernel<64, 128, 3><<<dim3(100), 256, 0, stream>>>(
      imgbf, imgwT, x, img_proj_b, 0, nullptr, pos_embed, 1568, 512, 768, 25, dflag);

  for (int i = 0; i < 4; ++i) {
    ln_kernel<<<dim3(1008), 256, 0, stream>>>(x, ln1_g, ln1_b, i * 512, h, 4032, dflag);
    gemm_kernel<64, 128, 0><<<dim3(756), 256, 0, stream>>>(
        h, qkvT + i * 786432, qkvb, nullptr, 0, nullptr, nullptr, 4032, 1536, 512, 63, dflag);
    attn_mfma_kernel<<<dim3(32, 8), 256, 0, stream>>>(qkvb, amask, ob);
    gemm_kernel<64, 128, 2><<<dim3(252), 256, 0, stream>>>(
        ob, wpT + i * 262144, x, b_proj, i * 512, x, nullptr, 4032, 512, 512, 63, dflag);
    ln_kernel<<<dim3(1008), 256, 0, stream>>>(x, ln2_g, ln2_b, i * 512, h, 4032, dflag);
    gemm_kernel<64, 128, 1><<<dim3(1008), 256, 0, stream>>>(
        h, fc1T + i * 1048576, ff, fc1_b, i * 2048, nullptr, nullptr, 4032, 2048, 512, 63, dflag);
    gemm_kernel<64, 128, 2><<<dim3(252), 256, 0, stream>>>(
        ff, fc2T + i * 1048576, x, fc2_b, i * 512, x, nullptr, 4032, 512, 2048, 63, dflag);
  }

  transpose_lnf<<<dim3(25320), 256, 0, stream>>>(
      out_w, outwT, x, lnf_g, lnf_b, xl, dflag);
  gemm256_kernel<<<dim3(1930), 512, 0, stream>>>(
      xl, outwT, d_out, out_b, 2464, 49408, 512, 10, dflag);
}

// Round 14
// 802.072 us; speedup vs baseline: 1.4257x; 1.0010x over previous
//
#include <hip/hip_runtime.h>
#include <hip/hip_bf16.h>
#include <stdint.h>

// ---------------------------------------------------------------------------
// MMTransformer: B=32, IMG_LEN=49, TXT_LEN=77, L=126, D=512, H=8, HK=64,
// FF=2048, NB=4, IMG_DIM=768, VOCAB=49408.
// Round 14: (1) qkv & fc1 -> 128x128 tiles under counted-vmcnt pipeline
// (round-8 regression was with drain-vmcnt; ratio now 32 MFMA : 8 ds_read);
// (2) out_w transpose folded into prep_all when ws_size allows un-aliased
// outwT (deterministic runtime branch; fallback = round-13 tail path);
// (3) T5 setprio around attn MFMA clusters. Core GEMM/attn math unchanged
// from round-13 green (802 us, absmax 0.0156).
// ---------------------------------------------------------------------------

using u16 = unsigned short;
typedef __attribute__((ext_vector_type(8))) __bf16 bf16x8v;
typedef __attribute__((ext_vector_type(4))) float f32x4;

__device__ __forceinline__ float bf2f(u16 u) {
  union { unsigned int i; float f; } x; x.i = ((unsigned int)u) << 16; return x.f;
}
__device__ __forceinline__ u16 f2bf(float f) {
  union { float f; unsigned int i; } u; u.f = f;
  unsigned int r = u.i + 0x7FFFu + ((u.i >> 16) & 1u);   // RNE
  return (u16)(r >> 16);
}
__device__ __forceinline__ float ld_f(const void* p, size_t i, int fl) {
  return fl ? ((const float*)p)[i] : bf2f(((const u16*)p)[i]);
}
__device__ __forceinline__ u16 ld_bf(const void* p, size_t i, int fl) {
  return fl ? f2bf(((const float*)p)[i]) : ((const u16*)p)[i];
}

__device__ __forceinline__ void async_copy16(const void* g, void* l) {
  __builtin_amdgcn_global_load_lds(
      (__attribute__((address_space(1))) void*)(g),
      (__attribute__((address_space(3))) void*)(l), 16, 0, 0);
}

__global__ void detect_kernel(const void* __restrict__ img, int* __restrict__ flag) {
  const int lane = threadIdx.x;
  const u16* p = (const u16*)img;
  int bad = 0;
#pragma unroll
  for (int i = 0; i < 4; ++i) {
    float v = bf2f(p[lane * 4 + i]);
    float av = fabsf(v);
    if (!(av <= 1e4f) || (av != 0.0f && av < 1e-30f)) bad++;
  }
#pragma unroll
  for (int off = 32; off; off >>= 1) bad += __shfl_xor(bad, off, 64);
  if (lane == 0) flag[0] = (bad > 16) ? 1 : 0;
}

__global__ void sentinel_kernel(float* out) {
  out[blockIdx.x * 256 + threadIdx.x] = 123456.0f;
}

// ---------------------------------------------------------------------------
// Layer GEMM (bf16 A): BN=128, BK=64, counted-vmcnt 2-buffer pipeline.
// ---------------------------------------------------------------------------
template <int BM, int BN, int EPI>
__global__ __launch_bounds__(256) void gemm_kernel(
    const u16* __restrict__ A, const u16* __restrict__ Bt, void* Cout,
    const void* __restrict__ bias, long boff, const float* resid,
    const void* __restrict__ pos, int M, int N, int K, int gridM,
    const int* __restrict__ fl)
{
  static_assert(BN == 128, "");
  static_assert(BM == 64 || BM == 128, "");
  constexpr int TILE_B = (BM + BN) * 128;
  constexpr int EPI_B = BM * BN * 2;
  constexpr int SMEM_B = (2 * TILE_B > EPI_B) ? 2 * TILE_B : EPI_B;
  __shared__ __align__(16) char smem[SMEM_B];

  const int tid = threadIdx.x;
  const int lane = tid & 63, wid = tid >> 6;
  const int wm = wid >> 1, wn = wid & 1;
  constexpr int FM = BM / 32, FN = 4;
  constexpr int ITA = BM / 32, ITB = BN / 32;
  constexpr int NLOADS = ITA + ITB;

  const int nwg = gridDim.x;
  const int q = nwg >> 3, r8 = nwg & 7;
  const int xcd = blockIdx.x & 7, idx = blockIdx.x >> 3;
  const int wgid = (xcd < r8 ? xcd * (q + 1) : r8 * (q + 1) + (xcd - r8) * q) + idx;
  const int tileM = (wgid % gridM) * BM, tileN = (wgid / gridM) * BN;

  f32x4 acc[FM][FN] = {};

  auto stage = [&](int buf, int kt) {
    char* base = smem + buf * TILE_B;
#pragma unroll
    for (int it = 0; it < ITA; ++it) {
      int ch = (wid * ITA + it) * 64 + lane;
      int row = ch >> 3, slot = ch & 7;
      int grow = tileM + row; grow = grow < M ? grow : (M - 1);
      async_copy16(A + (size_t)grow * K + kt * 64 + ((slot ^ (row & 7)) << 3),
                   base + (wid * ITA + it) * 1024);
    }
#pragma unroll
    for (int it = 0; it < ITB; ++it) {
      int ch = (wid * ITB + it) * 64 + lane;
      int row = ch >> 3, slot = ch & 7;
      async_copy16(Bt + (size_t)(tileN + row) * K + kt * 64 + ((slot ^ (row & 7)) << 3),
                   base + BM * 128 + (wid * ITB + it) * 1024);
    }
  };

  const int kSteps = K >> 6;
  stage(0, 0);
  int cur = 0;
  for (int kt = 0; kt < kSteps; ++kt) {
    if (kt + 1 < kSteps) {
      stage(cur ^ 1, kt + 1);
      asm volatile("s_waitcnt vmcnt(%0)" :: "i"(NLOADS) : "memory");
    } else {
      asm volatile("s_waitcnt vmcnt(0)" ::: "memory");
    }
    __builtin_amdgcn_s_barrier();
    __builtin_amdgcn_sched_barrier(0);
    const u16* lA = (const u16*)(smem + cur * TILE_B);
    const u16* lB = (const u16*)(smem + cur * TILE_B + BM * 128);
#pragma unroll
    for (int kk = 0; kk < 2; ++kk) {
      const int j = kk * 4 + (lane >> 4);
      bf16x8v af[FM], bfr[FN];
#pragma unroll
      for (int fm = 0; fm < FM; ++fm) {
        int rr = wm * (BM / 2) + fm * 16 + (lane & 15);
        af[fm] = *(const bf16x8v*)(lA + rr * 64 + ((j ^ (rr & 7)) << 3));
      }
#pragma unroll
      for (int fn = 0; fn < FN; ++fn) {
        int rn = wn * 64 + fn * 16 + (lane & 15);
        bfr[fn] = *(const bf16x8v*)(lB + rn * 64 + ((j ^ (rn & 7)) << 3));
      }
      __builtin_amdgcn_s_setprio(1);
#pragma unroll
      for (int fm = 0; fm < FM; ++fm)
#pragma unroll
        for (int fn = 0; fn < FN; ++fn)
          acc[fm][fn] = __builtin_amdgcn_mfma_f32_16x16x32_bf16(
              af[fm], bfr[fn], acc[fm][fn], 0, 0, 0);
      __builtin_amdgcn_s_setprio(0);
    }
    __builtin_amdgcn_sched_barrier(0);
    __builtin_amdgcn_s_barrier();
    cur ^= 1;
  }

  const int fla = (EPI == 0) ? 0 : *fl;
  const int row0l = wm * (BM / 2);
  const int col0l = wn * 64;

  auto store_bf16 = [&](bool do_bias, bool do_gelu) {
    u16* ep = (u16*)smem;
#pragma unroll
    for (int fm = 0; fm < FM; ++fm)
#pragma unroll
      for (int fn = 0; fn < FN; ++fn)
#pragma unroll
        for (int jj = 0; jj < 4; ++jj) {
          int rl = row0l + fm * 16 + ((lane >> 4) << 2) + jj;
          int cl = col0l + fn * 16 + (lane & 15);
          float t = acc[fm][fn][jj];
          if (do_bias) t += ld_f(bias, boff + tileN + cl, fla);
          if (do_gelu) t = 0.5f * t * (1.0f + erff(t * 0.70710678118654752f));
          ep[rl * BN + cl] = f2bf(t);
        }
    __syncthreads();
    for (int rr = tid >> 4; rr < BM; rr += 16) {
      int grow = tileM + rr;
      if (grow < M)
        *(uint4*)((u16*)Cout + (size_t)grow * N + tileN + (tid & 15) * 8) =
            *(const uint4*)(ep + rr * BN + (tid & 15) * 8);
    }
  };

  auto store_f32 = [&](bool do_resid, bool do_remap_pos) {
    float* epf = (float*)smem;
#pragma unroll
    for (int p = 0; p < 2; ++p) {
      __syncthreads();
      if (wm == p) {
#pragma unroll
        for (int fm = 0; fm < FM; ++fm)
#pragma unroll
          for (int fn = 0; fn < FN; ++fn)
#pragma unroll
            for (int jj = 0; jj < 4; ++jj) {
              int rl = fm * 16 + ((lane >> 4) << 2) + jj;
              int cl = col0l + fn * 16 + (lane & 15);
              float t = acc[fm][fn][jj] + ld_f(bias, boff + tileN + cl, fla);
              if (do_remap_pos) {
                int grow_t = tileM + p * (BM / 2) + rl;
                int ll = grow_t % 49;
                t += ld_f(pos, ll * 512 + tileN + cl, fla);
              }
              epf[rl * BN + cl] = t;
            }
      }
      __syncthreads();
      for (int rr = tid >> 5; rr < BM / 2; rr += 8) {
        int grow = tileM + p * (BM / 2) + rr;
        if (grow < M) {
          f32x4 t = *(const f32x4*)(epf + rr * BN + (tid & 31) * 4);
          if (do_resid)
            t += *(const f32x4*)(resid + (size_t)grow * N + tileN + (tid & 31) * 4);
          size_t orow = grow;
          if (do_remap_pos) orow = (size_t)(grow / 49) * 126 + grow % 49;
          *(f32x4*)((float*)Cout + orow * N + tileN + (tid & 31) * 4) = t;
        }
      }
    }
  };

  if constexpr (EPI == 0) store_bf16(false, false);
  else if constexpr (EPI == 1) store_bf16(true, true);
  else if constexpr (EPI == 2) store_f32(true, false);
  else if constexpr (EPI == 3) store_f32(false, true);
  else { if (fla) store_f32(false, false); else store_bf16(true, false); }
}

// ---------------------------------------------------------------------------
// 256x256 vocab GEMM: counted-vmcnt 2-buffer pipeline.
// ---------------------------------------------------------------------------
__global__ __launch_bounds__(512) void gemm256_kernel(
    const u16* __restrict__ A, const u16* __restrict__ Bt, void* Cout,
    const void* __restrict__ bias, int M, int N, int K, int gridM,
    const int* __restrict__ fl)
{
  constexpr int BM = 256, BN = 256;
  constexpr int TILE_B = (BM + BN) * 128;
  __shared__ __align__(16) char smem[2 * TILE_B];

  const int tid = threadIdx.x;
  const int lane = tid & 63, wid = tid >> 6;
  const int wm = wid >> 2, wn = wid & 3;

  const int nwg = gridDim.x;
  const int q = nwg >> 3, r8 = nwg & 7;
  const int xcd = blockIdx.x & 7, idx = blockIdx.x >> 3;
  const int wgid = (xcd < r8 ? xcd * (q + 1) : r8 * (q + 1) + (xcd - r8) * q) + idx;
  const int tileM = (wgid % gridM) * BM, tileN = (wgid / gridM) * BN;

  f32x4 acc[8][4] = {};

  auto stage = [&](int buf, int kt) {
    char* base = smem + buf * TILE_B;
#pragma unroll
    for (int it = 0; it < 4; ++it) {
      int ch = (wid * 4 + it) * 64 + lane;
      int row = ch >> 3, slot = ch & 7;
      int grow = tileM + row; grow = grow < M ? grow : (M - 1);
      async_copy16(A + (size_t)grow * K + kt * 64 + ((slot ^ (row & 7)) << 3),
                   base + (wid * 4 + it) * 1024);
    }
#pragma unroll
    for (int it = 0; it < 4; ++it) {
      int ch = (wid * 4 + it) * 64 + lane;
      int row = ch >> 3, slot = ch & 7;
      async_copy16(Bt + (size_t)(tileN + row) * K + kt * 64 + ((slot ^ (row & 7)) << 3),
                   base + BM * 128 + (wid * 4 + it) * 1024);
    }
  };

  const int kSteps = K >> 6;
  stage(0, 0);
  int cur = 0;
  for (int kt = 0; kt < kSteps; ++kt) {
    if (kt + 1 < kSteps) {
      stage(cur ^ 1, kt + 1);
      asm volatile("s_waitcnt vmcnt(8)" ::: "memory");
    } else {
      asm volatile("s_waitcnt vmcnt(0)" ::: "memory");
    }
    __builtin_amdgcn_s_barrier();
    __builtin_amdgcn_sched_barrier(0);
    const u16* lA = (const u16*)(smem + cur * TILE_B);
    const u16* lB = (const u16*)(smem + cur * TILE_B + BM * 128);
#pragma unroll
    for (int kk = 0; kk < 2; ++kk) {
      const int j = kk * 4 + (lane >> 4);
      bf16x8v bfr[4];
#pragma unroll
      for (int fn = 0; fn < 4; ++fn) {
        int rn = wn * 64 + fn * 16 + (lane & 15);
        bfr[fn] = *(const bf16x8v*)(lB + rn * 64 + ((j ^ (rn & 7)) << 3));
      }
#pragma unroll
      for (int mh = 0; mh < 2; ++mh) {
        bf16x8v af[4];
#pragma unroll
        for (int f = 0; f < 4; ++f) {
          int rr = wm * 128 + (mh * 4 + f) * 16 + (lane & 15);
          af[f] = *(const bf16x8v*)(lA + rr * 64 + ((j ^ (rr & 7)) << 3));
        }
        __builtin_amdgcn_s_setprio(1);
#pragma unroll
        for (int f = 0; f < 4; ++f)
#pragma unroll
          for (int fn = 0; fn < 4; ++fn)
            acc[mh * 4 + f][fn] = __builtin_amdgcn_mfma_f32_16x16x32_bf16(
                af[f], bfr[fn], acc[mh * 4 + f][fn], 0, 0, 0);
        __builtin_amdgcn_s_setprio(0);
      }
    }
    __builtin_amdgcn_sched_barrier(0);
    __builtin_amdgcn_s_barrier();
    cur ^= 1;
  }

  const int fla = *fl;
  if (fla) {
    float* epf = (float*)smem;
#pragma unroll
    for (int p = 0; p < 4; ++p) {
      __syncthreads();
      if (wm == (p >> 1)) {
#pragma unroll
        for (int fq = 0; fq < 4; ++fq) {
          int fm = (p & 1) * 4 + fq;
#pragma unroll
          for (int fn = 0; fn < 4; ++fn)
#pragma unroll
            for (int jj = 0; jj < 4; ++jj) {
              int rl = fq * 16 + ((lane >> 4) << 2) + jj;
              int cl = wn * 64 + fn * 16 + (lane & 15);
              epf[rl * 256 + cl] = acc[fm][fn][jj] + ld_f(bias, tileN + cl, 1);
            }
        }
      }
      __syncthreads();
      for (int rr = tid >> 6; rr < 64; rr += 8) {
        int grow = tileM + p * 64 + rr;
        if (grow < M)
          *(f32x4*)((float*)Cout + (size_t)grow * N + tileN + lane * 4) =
              *(const f32x4*)(epf + rr * 256 + lane * 4);
      }
    }
  } else {
    u16* ep = (u16*)smem;
    __syncthreads();
#pragma unroll
    for (int fm = 0; fm < 8; ++fm)
#pragma unroll
      for (int fn = 0; fn < 4; ++fn)
#pragma unroll
        for (int jj = 0; jj < 4; ++jj) {
          int rl = wm * 128 + fm * 16 + ((lane >> 4) << 2) + jj;
          int cl = wn * 64 + fn * 16 + (lane & 15);
          ep[rl * 256 + cl] = f2bf(acc[fm][fn][jj] + ld_f(bias, tileN + cl, 0));
        }
    __syncthreads();
    for (int rr = tid >> 5; rr < 256; rr += 16) {
      int grow = tileM + rr;
      if (grow < M)
        *(uint4*)((u16*)Cout + (size_t)grow * N + tileN + (tid & 31) * 8) =
            *(const uint4*)(ep + rr * 256 + (tid & 31) * 8);
    }
  }
}

// ---------------------------------------------------------------------------
// prep_all: weight transposes + img convert + txt embed (+ optionally the
// out_w transpose, when outwT is un-aliased) in ONE launch.
//   [0,12672)            32x32 transposes (imgw / qkv / wp / fc1 / fc2)
//   [12672,17376)        convert img_hidden -> imgbf
//   [17376,22304)        txt embed -> x
//   [22304,22304+24704)  out_w 512x49408 -> outwT (fused mode only)
// ---------------------------------------------------------------------------
__global__ __launch_bounds__(256) void prep_all(
    const void* __restrict__ imgw, const void* __restrict__ wq,
    const void* __restrict__ wk, const void* __restrict__ wv,
    const void* __restrict__ wp, const void* __restrict__ fc1,
    const void* __restrict__ fc2, const void* __restrict__ imgh,
    const void* __restrict__ txt, const void* __restrict__ pos,
    const void* __restrict__ out_w,
    u16* __restrict__ imgwT, u16* __restrict__ qkvT, u16* __restrict__ wpT,
    u16* __restrict__ fc1T, u16* __restrict__ fc2T,
    u16* __restrict__ imgbf, float* __restrict__ x, u16* __restrict__ outwT,
    const int* __restrict__ fl)
{
  const int fla = *fl;
  const int b = blockIdx.x;
  if (b >= 12672 && b < 22304) {
    if (b < 17376) {
      int i = (b - 12672) * 256 + threadIdx.x;
      if (i < 1204224) imgbf[i] = ld_bf(imgh, i, fla);
    } else {
      int idx = (b - 17376) * 256 + threadIdx.x;
      if (idx < 32 * 77 * 512) {
        int d = idx & 511, bt = idx >> 9;
        int t = bt % 77, bb = bt / 77;
        x[((size_t)(bb * 126 + 49 + t)) * 512 + d] =
            ld_f(txt, idx, fla) + ld_f(pos, (49 + t) * 512 + d, fla);
      }
    }
    return;
  }
  __shared__ u16 t[32][33];
  const void* in; u16* out; int R, C, cx, ry;
  size_t zi, zo;
  if (b >= 22304) {                     // fused out_w transpose
    int bb = b - 22304;
    in = out_w; out = outwT; R = 512; C = 49408;
    cx = bb % 1544; ry = bb / 1544; zi = 0; zo = 0;
  } else if (b < 384) {
    in = imgw; out = imgwT; R = 768; C = 512; zi = 0; zo = 0;
    cx = b & 15; ry = b >> 4;
  } else if (b < 3456) {
    int bb = b - 384;
    int z = bb >> 5, r2 = bb & 31;
    cx = r2 & 1; ry = r2 >> 1;
    int src = z >> 5, rem = z & 31, li = rem >> 3, hh = rem & 7;
    in = (src == 0) ? wq : (src == 1) ? wk : wv;
    out = qkvT; R = 512; C = 64;
    zi = (size_t)rem * (512 * 64);
    zo = (size_t)li * (1536 * 512) + (size_t)(src * 512 + hh * 64) * 512;
  } else if (b < 4480) {
    int bb = b - 3456;
    int z = bb >> 8, r2 = bb & 255;
    cx = r2 & 15; ry = r2 >> 4;
    in = wp; out = wpT; R = 512; C = 512;
    zi = (size_t)z * (512 * 512); zo = zi;
  } else if (b < 8576) {
    int bb = b - 4480;
    int z = bb >> 10, r2 = bb & 1023;
    cx = r2 & 63; ry = r2 >> 6;
    in = fc1; out = fc1T; R = 512; C = 2048;
    zi = (size_t)z * (512 * 2048); zo = zi;
  } else {
    int bb = b - 8576;
    int z = bb >> 10, r2 = bb & 1023;
    cx = r2 & 15; ry = r2 >> 4;
    in = fc2; out = fc2T; R = 2048; C = 512;
    zi = (size_t)z * (512 * 2048); zo = zi;
  }
  const int c0 = cx * 32, r0 = ry * 32;
  const int tx = threadIdx.x & 31, ty = threadIdx.x >> 5;
#pragma unroll
  for (int i = 0; i < 4; ++i)
    t[ty + 8 * i][tx] = ld_bf(in, zi + (size_t)(r0 + ty + 8 * i) * C + (c0 + tx), fla);
  __syncthreads();
#pragma unroll
  for (int i = 0; i < 4; ++i)
    out[zo + (size_t)(c0 + ty + 8 * i) * R + (r0 + tx)] = t[tx][ty + 8 * i];
}

// ---------------------------------------------------------------------------
// Tail: final LN only (fused mode) or out_w transpose + final LN (fallback).
// ---------------------------------------------------------------------------
__global__ __launch_bounds__(256) void lnf_kernel(
    const float* __restrict__ x, const void* __restrict__ gam,
    const void* __restrict__ bet, u16* __restrict__ xl,
    const int* __restrict__ fl)
{
  const int fla = *fl;
  const int lane = threadIdx.x & 63, wid = threadIdx.x >> 6;
  const int r = blockIdx.x * 4 + wid;
  if (r >= 2464) return;
  int bb = r / 77, t = r % 77;
  int srow = bb * 126 + 49 + t;
  const float* xr = x + (size_t)srow * 512 + lane * 8;
  f32x4 v0 = *(const f32x4*)xr;
  f32x4 v1 = *(const f32x4*)(xr + 4);
  float s = v0[0] + v0[1] + v0[2] + v0[3] + v1[0] + v1[1] + v1[2] + v1[3];
#pragma unroll
  for (int off = 32; off; off >>= 1) s += __shfl_xor(s, off, 64);
  const float mu = s * (1.0f / 512.0f);
  float q2 = 0.f;
#pragma unroll
  for (int j = 0; j < 4; ++j) { v0[j] -= mu; q2 += v0[j] * v0[j]; }
#pragma unroll
  for (int j = 0; j < 4; ++j) { v1[j] -= mu; q2 += v1[j] * v1[j]; }
#pragma unroll
  for (int off = 32; off; off >>= 1) q2 += __shfl_xor(q2, off, 64);
  const float inv = rsqrtf(q2 * (1.0f / 512.0f) + 1e-5f);
  union { u16 a[8]; uint4 v; } ou;
#pragma unroll
  for (int j = 0; j < 8; ++j) {
    float d = (j < 4) ? v0[j] : v1[j - 4];
    ou.a[j] = f2bf(d * inv * ld_f(gam, lane * 8 + j, fla)
                   + ld_f(bet, lane * 8 + j, fla));
  }
  *(uint4*)(xl + (size_t)r * 512 + lane * 8) = ou.v;
}

__global__ __launch_bounds__(256) void transpose_lnf(
    const void* __restrict__ out_w, u16* __restrict__ outwT,
    const float* __restrict__ x, const void* __restrict__ gam,
    const void* __restrict__ bet, u16* __restrict__ xl,
    const int* __restrict__ fl)
{
  const int fla = *fl;
  const int b = blockIdx.x;
  if (b >= 24704) {
    const int lane = threadIdx.x & 63, wid = threadIdx.x >> 6;
    const int r = (b - 24704) * 4 + wid;
    if (r >= 2464) return;
    int bb = r / 77, t = r % 77;
    int srow = bb * 126 + 49 + t;
    const float* xr = x + (size_t)srow * 512 + lane * 8;
    f32x4 v0 = *(const f32x4*)xr;
    f32x4 v1 = *(const f32x4*)(xr + 4);
    float s = v0[0] + v0[1] + v0[2] + v0[3] + v1[0] + v1[1] + v1[2] + v1[3];
#pragma unroll
    for (int off = 32; off; off >>= 1) s += __shfl_xor(s, off, 64);
    const float mu = s * (1.0f / 512.0f);
    float q2 = 0.f;
#pragma unroll
    for (int j = 0; j < 4; ++j) { v0[j] -= mu; q2 += v0[j] * v0[j]; }
#pragma unroll
    for (int j = 0; j < 4; ++j) { v1[j] -= mu; q2 += v1[j] * v1[j]; }
#pragma unroll
    for (int off = 32; off; off >>= 1) q2 += __shfl_xor(q2, off, 64);
    const float inv = rsqrtf(q2 * (1.0f / 512.0f) + 1e-5f);
    union { u16 a[8]; uint4 v; } ou;
#pragma unroll
    for (int j = 0; j < 8; ++j) {
      float d = (j < 4) ? v0[j] : v1[j - 4];
      ou.a[j] = f2bf(d * inv * ld_f(gam, lane * 8 + j, fla)
                     + ld_f(bet, lane * 8 + j, fla));
    }
    *(uint4*)(xl + (size_t)r * 512 + lane * 8) = ou.v;
    return;
  }
  __shared__ u16 t[32][33];
  const int cx = b % 1544, ry = b / 1544;
  const int c0 = cx * 32, r0 = ry * 32;
  const int tx = threadIdx.x & 31, ty = threadIdx.x >> 5;
#pragma unroll
  for (int i = 0; i < 4; ++i)
    t[ty + 8 * i][tx] =
        ld_bf(out_w, (size_t)(r0 + ty + 8 * i) * 49408 + (c0 + tx), fla);
  __syncthreads();
#pragma unroll
  for (int i = 0; i < 4; ++i)
    outwT[(size_t)(c0 + ty + 8 * i) * 512 + (r0 + tx)] = t[tx][ty + 8 * i];
}

// ---------------------------------------------------------------------------
// MFMA attention: one block per (b,h), 256 threads / 4 waves.
// ---------------------------------------------------------------------------
__global__ __launch_bounds__(256) void attn_mfma_kernel(
    const u16* __restrict__ qkv, const int* __restrict__ amask,
    u16* __restrict__ o)
{
  const int b = blockIdx.x, hh = blockIdx.y;
  __shared__ __align__(16) u16 Qs[128 * 64];
  __shared__ __align__(16) u16 Ks[128 * 64];
  __shared__ __align__(16) u16 Vt[64 * 136];
  __shared__ float Sf[128 * 129];
  __shared__ __align__(16) u16 Ps[128 * 128];
  __shared__ float padK[128];
  const int tid = threadIdx.x, lane = tid & 63, wid = tid >> 6;

  for (int ch = tid; ch < 1024; ch += 256) {
    int row = ch >> 3, slot = ch & 7;
    int gm = row < 126 ? row : 125;
    size_t base = ((size_t)(b * 126 + gm)) * 1536 + hh * 64;
    int gslot = slot ^ (row & 7);
    *(uint4*)(Qs + row * 64 + slot * 8) = *(const uint4*)(qkv + base + gslot * 8);
    *(uint4*)(Ks + row * 64 + slot * 8) = *(const uint4*)(qkv + base + 512 + gslot * 8);
  }
  for (int m = wid; m < 126; m += 4) {
    size_t base = ((size_t)(b * 126 + m)) * 1536 + hh * 64 + 1024;
    Vt[lane * 136 + m] = qkv[base + lane];
  }
  if (wid == 0) { Vt[lane * 136 + 126] = 0; Vt[lane * 136 + 127] = 0; }
  for (int j = tid; j < 128; j += 256) {
    float kv = 0.0f;
    if (j < 49) kv = 1.0f;
    else if (j < 126) kv = (amask[b * 77 + (j - 49)] != 0) ? 1.0f : 0.0f;
    padK[j] = kv;
  }
  __syncthreads();

  f32x4 accS[2][8] = {};
#pragma unroll
  for (int ks = 0; ks < 2; ++ks) {
    const int j = ks * 4 + (lane >> 4);
    bf16x8v qf[2], kf[8];
#pragma unroll
    for (int fr = 0; fr < 2; ++fr) {
      int rr = (wid * 2 + fr) * 16 + (lane & 15);
      qf[fr] = *(const bf16x8v*)(Qs + rr * 64 + ((j ^ (rr & 7)) << 3));
    }
#pragma unroll
    for (int fc = 0; fc < 8; ++fc) {
      int rn = fc * 16 + (lane & 15);
      kf[fc] = *(const bf16x8v*)(Ks + rn * 64 + ((j ^ (rn & 7)) << 3));
    }
    __builtin_amdgcn_s_setprio(1);
#pragma unroll
    for (int fr = 0; fr < 2; ++fr)
#pragma unroll
      for (int fc = 0; fc < 8; ++fc)
        accS[fr][fc] = __builtin_amdgcn_mfma_f32_16x16x32_bf16(
            qf[fr], kf[fc], accS[fr][fc], 0, 0, 0);
    __builtin_amdgcn_s_setprio(0);
  }
#pragma unroll
  for (int fr = 0; fr < 2; ++fr)
#pragma unroll
    for (int fc = 0; fc < 8; ++fc)
#pragma unroll
      for (int jj = 0; jj < 4; ++jj) {
        int row = (wid * 2 + fr) * 16 + ((lane >> 4) << 2) + jj;
        int col = fc * 16 + (lane & 15);
        Sf[row * 129 + col] = accS[fr][fc][jj];
      }
  __syncthreads();

  const float scale = 0.04419417382415922f;  // 512^-0.5 (full-D, faithful)
  for (int r = wid; r < 128; r += 4) {
    const int m0 = lane, m1 = lane + 64;
    float s0 = Sf[r * 129 + m0] * scale;
    float s1 = Sf[r * 129 + m1] * scale;
    bool kp0 = (padK[m0] != 0.f) && (m0 < 49 || r < 49 || m0 <= r);
    bool kp1 = (padK[m1] != 0.f) && (r < 49 || m1 <= r);
    float e0 = kp0 ? s0 : -1e30f;
    float e1 = kp1 ? s1 : -1e30f;
    float mx = fmaxf(e0, e1);
#pragma unroll
    for (int off = 32; off; off >>= 1) mx = fmaxf(mx, __shfl_xor(mx, off, 64));
    float p0 = kp0 ? __expf(s0 - mx) : 0.f;
    float p1 = kp1 ? __expf(s1 - mx) : 0.f;
    float sm = p0 + p1;
#pragma unroll
    for (int off = 32; off; off >>= 1) sm += __shfl_xor(sm, off, 64);
    float inv = 1.0f / sm;
    Ps[r * 128 + (((m0 >> 3) ^ (r & 7)) << 3) + (m0 & 7)] = f2bf(p0 * inv);
    Ps[r * 128 + (((m1 >> 3) ^ (r & 7)) << 3) + (m1 & 7)] = f2bf(p1 * inv);
  }
  __syncthreads();

  f32x4 accO[2][4] = {};
#pragma unroll
  for (int ks = 0; ks < 4; ++ks) {
    const int j = ks * 4 + (lane >> 4);
    bf16x8v pf[2], vf[4];
#pragma unroll
    for (int fr = 0; fr < 2; ++fr) {
      int rr = (wid * 2 + fr) * 16 + (lane & 15);
      pf[fr] = *(const bf16x8v*)(Ps + rr * 128 + ((j ^ (rr & 7)) << 3));
    }
#pragma unroll
    for (int fc = 0; fc < 4; ++fc) {
      int rn = fc * 16 + (lane & 15);
      vf[fc] = *(const bf16x8v*)(Vt + rn * 136 + (j << 3));
    }
    __builtin_amdgcn_s_setprio(1);
#pragma unroll
    for (int fr = 0; fr < 2; ++fr)
#pragma unroll
      for (int fc = 0; fc < 4; ++fc)
        accO[fr][fc] = __builtin_amdgcn_mfma_f32_16x16x32_bf16(
            pf[fr], vf[fc], accO[fr][fc], 0, 0, 0);
    __builtin_amdgcn_s_setprio(0);
  }

  u16* Ol = Qs;                                       // [128][64]
  __syncthreads();
#pragma unroll
  for (int fr = 0; fr < 2; ++fr)
#pragma unroll
    for (int fc = 0; fc < 4; ++fc)
#pragma unroll
      for (int jj = 0; jj < 4; ++jj) {
        int row = (wid * 2 + fr) * 16 + ((lane >> 4) << 2) + jj;
        int col = fc * 16 + (lane & 15);
        Ol[row * 64 + col] = f2bf(accO[fr][fc][jj]);
      }
  __syncthreads();
  for (int r = tid >> 3; r < 126; r += 32) {
    *(uint4*)(o + ((size_t)(b * 126 + r)) * 512 + hh * 64 + (tid & 7) * 8) =
        *(const uint4*)(Ol + r * 64 + (tid & 7) * 8);
  }
}

// LayerNorm over D=512, wave-per-row (4 rows/block, no LDS/barriers).
__global__ __launch_bounds__(256) void ln_kernel(
    const float* __restrict__ x, const void* __restrict__ gam,
    const void* __restrict__ bet, long goff, u16* __restrict__ out,
    int nrows, const int* __restrict__ fl)
{
  const int fla = *fl;
  const int lane = threadIdx.x & 63, wid = threadIdx.x >> 6;
  const int r = blockIdx.x * 4 + wid;
  if (r >= nrows) return;
  const float* xr = x + (size_t)r * 512 + lane * 8;
  f32x4 v0 = *(const f32x4*)xr;
  f32x4 v1 = *(const f32x4*)(xr + 4);
  float s = v0[0] + v0[1] + v0[2] + v0[3] + v1[0] + v1[1] + v1[2] + v1[3];
#pragma unroll
  for (int off = 32; off; off >>= 1) s += __shfl_xor(s, off, 64);
  const float mu = s * (1.0f / 512.0f);
  float q2 = 0.f;
#pragma unroll
  for (int j = 0; j < 4; ++j) { v0[j] -= mu; q2 += v0[j] * v0[j]; }
#pragma unroll
  for (int j = 0; j < 4; ++j) { v1[j] -= mu; q2 += v1[j] * v1[j]; }
#pragma unroll
  for (int off = 32; off; off >>= 1) q2 += __shfl_xor(q2, off, 64);
  const float inv = rsqrtf(q2 * (1.0f / 512.0f) + 1e-5f);
  union { u16 a[8]; uint4 v; } ou;
#pragma unroll
  for (int j = 0; j < 8; ++j) {
    float d = (j < 4) ? v0[j] : v1[j - 4];
    ou.a[j] = f2bf(d * inv * ld_f(gam, goff + lane * 8 + j, fla)
                   + ld_f(bet, goff + lane * 8 + j, fla));
  }
  *(uint4*)(out + (size_t)r * 512 + lane * 8) = ou.v;
}

// ---------------------------------------------------------------------------
extern "C" void kernel_launch(void* const* d_in, const int* in_sizes, int n_in,
                              void* d_out, int out_size, void* d_ws, size_t ws_size,
                              hipStream_t stream)
{
  (void)in_sizes; (void)n_in; (void)out_size;
  const void* img_hidden = d_in[0];
  const void* txt_emb    = d_in[1];
  const void* img_proj_w = d_in[2];
  const void* img_proj_b = d_in[3];
  const void* pos_embed  = d_in[4];
  const void* wq    = d_in[5];
  const void* wk    = d_in[6];
  const void* wv    = d_in[7];
  const void* w_proj = d_in[8];
  const void* b_proj = d_in[9];
  const void* ln1_g = d_in[10];
  const void* ln1_b = d_in[11];
  const void* ln2_g = d_in[12];
  const void* ln2_b = d_in[13];
  const void* fc1_w = d_in[14];
  const void* fc1_b = d_in[15];
  const void* fc2_w = d_in[16];
  const void* fc2_b = d_in[17];
  const void* lnf_g = d_in[18];
  const void* lnf_b = d_in[19];
  const void* out_w = d_in[20];
  const void* out_b = d_in[21];
  const int* amask  = (const int*)d_in[22];

  char* ws = (char*)d_ws;
  size_t off = 0;
  auto alloc = [&](size_t bytes) {
    void* p = ws + off; off += (bytes + 255) & ~(size_t)255; return p;
  };
  int* dflag = (int*)alloc(256);
  u16* imgbf = (u16*)alloc(1204224ull * 2);
  float* x   = (float*)alloc(4032ull * 512 * 4);
  u16* xl    = (u16*)alloc(2464ull * 512 * 2);
  const size_t uni0 = off;
  u16* imgwT = (u16*)alloc(512ull * 768 * 2);
  u16* qkvT  = (u16*)alloc(4ull * 1536 * 512 * 2);
  u16* wpT   = (u16*)alloc(4ull * 512 * 512 * 2);
  u16* fc1T  = (u16*)alloc(4ull * 2048 * 512 * 2);
  u16* fc2T  = (u16*)alloc(4ull * 512 * 2048 * 2);
  u16* h     = (u16*)alloc(4032ull * 512 * 2);
  u16* qkvb  = (u16*)alloc(4032ull * 1536 * 2);
  u16* ob    = (u16*)alloc(4032ull * 512 * 2);
  u16* ff    = (u16*)alloc(4032ull * 2048 * 2);

  if (ws_size < off) {
    sentinel_kernel<<<dim3(16), 256, 0, stream>>>((float*)d_out);
    return;
  }
  // outwT: un-aliased (after everything) if ws allows -> fold out_w transpose
  // into prep_all; else alias the loop-dead union region and transpose at tail.
  const size_t OUTWT_B = ((49408ull * 512 * 2) + 255) & ~(size_t)255;
  const bool fuseT = (ws_size >= off + OUTWT_B);
  u16* outwT = fuseT ? (u16*)(ws + off) : (u16*)(ws + uni0);

  detect_kernel<<<dim3(1), 64, 0, stream>>>(img_hidden, dflag);
  prep_all<<<dim3(fuseT ? 47008 : 22304), 256, 0, stream>>>(
      img_proj_w, wq, wk, wv, w_proj, fc1_w, fc2_w, img_hidden, txt_emb,
      pos_embed, out_w, imgwT, qkvT, wpT, fc1T, fc2T, imgbf, x, outwT, dflag);

  gemm_kernel<64, 128, 3><<<dim3(100), 256, 0, stream>>>(
      imgbf, imgwT, x, img_proj_b, 0, nullptr, pos_embed, 1568, 512, 768, 25, dflag);

  for (int i = 0; i < 4; ++i) {
    ln_kernel<<<dim3(1008), 256, 0, stream>>>(x, ln1_g, ln1_b, i * 512, h, 4032, dflag);
    gemm_kernel<128, 128, 0><<<dim3(384), 256, 0, stream>>>(
        h, qkvT + i * 786432, qkvb, nullptr, 0, nullptr, nullptr, 4032, 1536, 512, 32, dflag);
    attn_mfma_kernel<<<dim3(32, 8), 256, 0, stream>>>(qkvb, amask, ob);
    gemm_kernel<64, 128, 2><<<dim3(252), 256, 0, stream>>>(
        ob, wpT + i * 262144, x, b_proj, i * 512, x, nullptr, 4032, 512, 512, 63, dflag);
    ln_kernel<<<dim3(1008), 256, 0, stream>>>(x, ln2_g, ln2_b, i * 512, h, 4032, dflag);
    gemm_kernel<128, 128, 1><<<dim3(512), 256, 0, stream>>>(
        h, fc1T + i * 1048576, ff, fc1_b, i * 2048, nullptr, nullptr, 4032, 2048, 512, 32, dflag);
    gemm_kernel<64, 128, 2><<<dim3(252), 256, 0, stream>>>(
        ff, fc2T + i * 1048576, x, fc2_b, i * 512, x, nullptr, 4032, 512, 2048, 63, dflag);
  }

  if (fuseT) {
    lnf_kernel<<<dim3(616), 256, 0, stream>>>(x, lnf_g, lnf_b, xl, dflag);
  } else {
    transpose_lnf<<<dim3(25320), 256, 0, stream>>>(
        out_w, outwT, x, lnf_g, lnf_b, xl, dflag);
  }
  gemm256_kernel<<<dim3(1930), 512, 0, stream>>>(
      xl, outwT, d_out, out_b, 2464, 49408, 512, 10, dflag);
}